// Round 6
// baseline (290.106 us; speedup 1.0000x reference)
//
#include <hip/hip_runtime.h>
#include <stdint.h>

// ---------------------------------------------------------------------------
// GeometricAttention: x@Wqkv -> RoPE -> causal MHA -> @Wo -> blade mixing
// B=2 T=2048 N=8 D=128, d_model=1024. bf16 MFMA pipeline, fp32 accum.
// ---------------------------------------------------------------------------

typedef __attribute__((ext_vector_type(8)))  __bf16 bf16x8;
typedef __attribute__((ext_vector_type(8)))  uint16_t u16x8;
typedef __attribute__((ext_vector_type(4)))  float  f32x4;
typedef __attribute__((ext_vector_type(16))) float  f32x16;

__device__ __forceinline__ uint16_t f2bf(float f) {
    uint32_t u = __float_as_uint(f);
    u += 0x7FFFu + ((u >> 16) & 1u);           // RNE
    return (uint16_t)(u >> 16);
}
__device__ __forceinline__ float bf2f(uint16_t h) {
    return __uint_as_float(((uint32_t)h) << 16);
}

__device__ __forceinline__ void gload_lds16(const void* g, void* l) {
    __builtin_amdgcn_global_load_lds(
        (__attribute__((address_space(1))) void*)g,
        (__attribute__((address_space(3))) void*)l, 16, 0, 0);
}

__device__ __forceinline__ void store_out(uint16_t* p, float v) { *p = f2bf(v); }
__device__ __forceinline__ void store_out(float* p, float v)    { *p = v; }

// ---------------------------------------------------------------- cast fp32->bf16
__global__ __launch_bounds__(256) void k_cast(const float* __restrict__ in,
                                              uint16_t* __restrict__ out, int n) {
    int i = blockIdx.x * 256 + threadIdx.x;          // one float4 per thread
    if (i * 4 >= n) return;
    float4 v = ((const float4*)in)[i];
    ushort4 o = make_ushort4(f2bf(v.x), f2bf(v.y), f2bf(v.z), f2bf(v.w));
    ((ushort4*)out)[i] = o;
}

// ------------------------------------------------- transpose W [K][N] -> Wt [N][K] bf16
__global__ __launch_bounds__(256) void k_wtrans(const float* __restrict__ W,
                                                uint16_t* __restrict__ Wt,
                                                int K, int N) {
    __shared__ uint16_t tile[64][65];
    const int k0 = blockIdx.y * 64, n0 = blockIdx.x * 64;
    const int c = threadIdx.x & 63, r4 = threadIdx.x >> 6;
#pragma unroll
    for (int i = 0; i < 16; ++i) {
        int r = r4 + i * 4;
        tile[r][c] = f2bf(W[(size_t)(k0 + r) * N + n0 + c]);
    }
    __syncthreads();
#pragma unroll
    for (int i = 0; i < 16; ++i) {
        int r = r4 + i * 4;
        Wt[(size_t)(n0 + r) * K + k0 + c] = tile[c][r];
    }
}

// ---------------------------------------------------------------- RoPE tables
__global__ __launch_bounds__(256) void k_tab(float* __restrict__ ct,
                                             float* __restrict__ st) {
    int i = blockIdx.x * 256 + threadIdx.x;          // 2048*64
    int t = i >> 6, f = i & 63;
    float inv = expf(-(float)f * 0.14391156830441f); // ln(10000)/64
    float ang = (float)t * inv;
    ct[i] = cosf(ang);
    st[i] = sinf(ang);
}

// ------------------------------------------------------- m97-style bf16 GEMM
// C[M][N] = A[M][K] * Bt[N][K]^T ; 128x128 tile, BK=32, 4 waves
template <typename OutT>
__global__ __launch_bounds__(256) void k_gemm(const uint16_t* __restrict__ A,
                                              const uint16_t* __restrict__ Bt,
                                              OutT* __restrict__ C,
                                              int M, int N, int K) {
    __shared__ uint16_t Atile[128 * 32];
    __shared__ uint16_t Btile[128 * 32];
    const int m0 = blockIdx.y << 7, n0 = blockIdx.x << 7;
    const int tid = threadIdx.x;
    const int l = tid & 63, w = tid >> 6;
    const int lr = l & 15, lg = l >> 4;
    const int wm = (w >> 1) << 6, wn = (w & 1) << 6;

    f32x4 acc[4][4];
#pragma unroll
    for (int i = 0; i < 4; ++i)
#pragma unroll
        for (int j = 0; j < 4; ++j) acc[i][j] = (f32x4){0.f, 0.f, 0.f, 0.f};

    const int nk = K >> 5;
    for (int kt = 0; kt < nk; ++kt) {
        const int k0 = kt << 5;
        __syncthreads();
#pragma unroll
        for (int c = 0; c < 4; ++c) {
            int idx = c * 256 + tid;                 // 0..1023, wave-contiguous
            if (idx < 512) {
                int r = idx >> 2, kc = (idx & 3) << 3;
                gload_lds16(A + (size_t)(m0 + r) * K + k0 + kc, &Atile[idx * 8]);
            } else {
                int i2 = idx - 512;
                int r = i2 >> 2, kc = (i2 & 3) << 3;
                gload_lds16(Bt + (size_t)(n0 + r) * K + k0 + kc, &Btile[i2 * 8]);
            }
        }
        __syncthreads();
        bf16x8 af[4], bfv[4];
#pragma unroll
        for (int i = 0; i < 4; ++i) {
            af[i]  = *(const bf16x8*)(&Atile[(wm + i * 16 + lr) * 32 + lg * 8]);
            bfv[i] = *(const bf16x8*)(&Btile[(wn + i * 16 + lr) * 32 + lg * 8]);
        }
#pragma unroll
        for (int mi = 0; mi < 4; ++mi)
#pragma unroll
            for (int ni = 0; ni < 4; ++ni)
                acc[mi][ni] = __builtin_amdgcn_mfma_f32_16x16x32_bf16(
                    af[mi], bfv[ni], acc[mi][ni], 0, 0, 0);
    }
    // C/D layout: col = lane&15, row = (lane>>4)*4 + reg   [m89-verified]
#pragma unroll
    for (int mi = 0; mi < 4; ++mi)
#pragma unroll
        for (int ni = 0; ni < 4; ++ni)
#pragma unroll
            for (int r = 0; r < 4; ++r) {
                int row = m0 + wm + mi * 16 + lg * 4 + r;
                int col = n0 + wn + ni * 16 + lr;
                store_out(&C[(size_t)row * N + col], acc[mi][ni][r]);
            }
}

// ------------------------------------------- RoPE apply: QKV -> Q,K [h][T][D]
__global__ __launch_bounds__(256) void k_rope(const uint16_t* __restrict__ qkv,
                                              const float* __restrict__ ct,
                                              const float* __restrict__ st,
                                              uint16_t* __restrict__ Qo,
                                              uint16_t* __restrict__ Ko) {
    int idx = blockIdx.x * 256 + threadIdx.x;        // B*T*N*64 pairs
    int d  = idx & 63;
    int n  = (idx >> 6) & 7;
    int bt = idx >> 9;
    int t  = bt & 2047, b = bt >> 11;
    float c = ct[t * 64 + d], s = st[t * 64 + d];
    size_t base = (size_t)bt * 3072 + n * 128 + d;
    float q1 = bf2f(qkv[base]),        q2 = bf2f(qkv[base + 64]);
    float k1 = bf2f(qkv[base + 1024]), k2 = bf2f(qkv[base + 1024 + 64]);
    size_t ob = ((size_t)(b * 8 + n) * 2048 + t) * 128 + d;
    Qo[ob]      = f2bf(q1 * c - q2 * s);
    Qo[ob + 64] = f2bf(q2 * c + q1 * s);
    Ko[ob]      = f2bf(k1 * c - k2 * s);
    Ko[ob + 64] = f2bf(k2 * c + k1 * s);
}

// -------------------------------------- V transpose: QKV v-part -> Vt [h][D][T]
__global__ __launch_bounds__(256) void k_vtrans(const uint16_t* __restrict__ qkv,
                                                uint16_t* __restrict__ Vt) {
    __shared__ uint16_t tile[64][65];
    const int h = blockIdx.z, b = h >> 3, n = h & 7;
    const int t0 = blockIdx.y * 64, d0 = blockIdx.x * 64;
    const int c = threadIdx.x & 63, r4 = threadIdx.x >> 6;
#pragma unroll
    for (int i = 0; i < 16; ++i) {
        int r = r4 + i * 4;                          // t offset
        tile[r][c] = qkv[(size_t)(b * 2048 + t0 + r) * 3072 + 2048 + n * 128 + d0 + c];
    }
    __syncthreads();
#pragma unroll
    for (int i = 0; i < 16; ++i) {
        int r = r4 + i * 4;                          // d offset
        Vt[((size_t)h * 128 + d0 + r) * 2048 + t0 + c] = tile[c][r];
    }
}

// --------------------------------------------------- causal flash attention
// R6: split-K chunks. Each block = one chunk of <=8 bodies (1 body = 64 k,
// two 32-k tiles split across wave parities) of one q-tile. 1280 near-uniform
// blocks (heavy chunks dispatched first) + 4 blocks/CU (33 KB LDS) -> 4
// waves/SIMD SUSTAINED (fixes the R3/R5 occupancy collapse: exact-capacity
// grids with heavy/light pairing left 1 wave/SIMD for most of the runtime).
// K direct global->reg (no LDS); V in a 4-slot LDS ring via global_load_lds
// (linear dest, inverse-swizzled source); per body: {vmcnt(0); barrier;
// issue STAGE(p+1)+LOADK(next); QK; softmax->paf (T12, in-reg); PV}.
// Chunk partials (unnormalized O bf16 + m,l f32) merged by k_amerge.
// Lane maps (m74/m101): A row=l&31,k=8h+e; B col=l&31; C col=l&31,
// row=(r&3)+8(r>>2)+4h.
__global__ __launch_bounds__(256, 4) void k_attn(const uint16_t* __restrict__ Qg,
                                                 const uint16_t* __restrict__ Kg,
                                                 const uint16_t* __restrict__ Vtg,
                                                 uint16_t* __restrict__ pbuf,
                                                 float* __restrict__ mlg) {
    __shared__ char  Vring[4 * 8192];                // 4 V tiles (32k x 128d)
    __shared__ float mlbuf[2][2][32];

    const int h = blockIdx.x;
    int s = blockIdx.y, qt = 31, ci = 0;             // slot -> (qt, ci), qt desc
    for (int q = 31; q >= 0; --q) {
        int nc = (q + 8) >> 3;
        if (s < nc) { qt = q; ci = s; break; }
        s -= nc;
    }
    const int slot = h * 80 + blockIdx.y;            // partial-storage index
    const int p0   = ci * 8;
    const int pend = min(p0 + 8, qt + 1);
    const int q0 = qt * 64;
    const int tid = threadIdx.x;
    const int l = tid & 63, w = tid >> 6;
    const int g = w & 1, par = w >> 1;               // q-group, k-parity
    const int c31 = l & 31, hh = l >> 5;
    const int lastT = 2 * qt + g;                    // diagonal tile for group g
    const size_t headTD = (size_t)h * (2048 * 128);
    const uint16_t* Kh = Kg + headTD;
    const uint16_t* Vh = Vtg + headTD;

    // Q in registers: B-frag col=q=c31, contraction d = 16t + 8hh + e
    bf16x8 qB[8];
    {
        const uint16_t* qp = Qg + headTD + (size_t)(q0 + 32 * g + c31) * 128 + hh * 8;
#pragma unroll
        for (int t = 0; t < 8; ++t) qB[t] = *(const bf16x8*)(qp + t * 16);
    }

    f32x16 acc[4];                                   // O[q-rows][dt*32+c31]
#pragma unroll
    for (int dt = 0; dt < 4; ++dt)
#pragma unroll
        for (int r = 0; r < 16; ++r) acc[dt][r] = 0.f;
    float mrun = -1e30f, lrun = 0.f;                 // per-lane row q=c31 (hh-split)
    bf16x8 paf[2];

    const float SL2E = 0.08838834764831845f * 1.4426950408889634f; // scale*log2e

    auto LOADK = [&](bf16x8* d, int t) {             // A-frags: K[t*32+c31][16i+8hh+e]
        const uint16_t* kp = Kh + (size_t)(t * 32 + c31) * 128 + hh * 8;
#pragma unroll
        for (int i = 0; i < 8; ++i) d[i] = *(const bf16x8*)(kp + i * 16);
    };
    auto STAGE = [&](int pp) {                       // stage V tiles 2pp, 2pp+1
#pragma unroll
        for (int i = 0; i < 4; ++i) {
            int u2 = i * 256 + tid;
            int tt = 2 * pp + (u2 >> 9);
            int uu = u2 & 511;
            int d  = uu >> 2, c16 = uu & 3;
            gload_lds16(Vh + (size_t)d * 2048 + tt * 32 + (c16 ^ ((d >> 1) & 3)) * 8,
                        Vring + (tt & 3) * 8192 + d * 64 + c16 * 16);
        }
    };
    auto PV = [&](int t) {                           // O += P V for tile t
        const char* Vb = Vring + (t & 3) * 8192;
        __builtin_amdgcn_s_setprio(1);
#pragma unroll
        for (int j = 0; j < 2; ++j)
#pragma unroll
            for (int dt = 0; dt < 4; ++dt) {
                int dr = dt * 32 + c31;
                bf16x8 vf = *(const bf16x8*)(Vb + dr * 64 +
                             ((j * 32 + hh * 16) ^ (((dr >> 1) & 3) << 4)));
                acc[dt] = __builtin_amdgcn_mfma_f32_32x32x16_bf16(paf[j], vf, acc[dt], 0, 0, 0);
            }
        __builtin_amdgcn_s_setprio(0);
    };
    auto BODY = [&](int p, bf16x8* kc, bf16x8* kn) {
        asm volatile("s_waitcnt vmcnt(0)" ::: "memory"); // prev body's loads done
        __builtin_amdgcn_s_barrier();
        __builtin_amdgcn_sched_barrier(0);
        if (p + 1 < pend) { STAGE(p + 1); LOADK(kn, 2 * (p + 1) + par); }
        const int t = 2 * p + par;
        if (t <= lastT) {
            f32x16 sv;
#pragma unroll
            for (int r = 0; r < 16; ++r) sv[r] = 0.f;
            __builtin_amdgcn_s_setprio(1);
#pragma unroll
            for (int i = 0; i < 8; ++i)
                sv = __builtin_amdgcn_mfma_f32_32x32x16_bf16(kc[i], qB[i], sv, 0, 0, 0);
            __builtin_amdgcn_s_setprio(0);
            if (t == lastT) {                        // diagonal tile mask
#pragma unroll
                for (int r = 0; r < 16; ++r)
                    if ((r & 3) + 8 * (r >> 2) + 4 * hh > c31) sv[r] = -1e30f;
            }
            float pml = sv[0];
#pragma unroll
            for (int r = 1; r < 16; ++r) pml = fmaxf(pml, sv[r]);
            if (!__all(pml * SL2E <= mrun + 11.f)) { // rare: true max + rescale
                float mx = fmaxf(pml, __shfl_xor(pml, 32, 64));
                float mn = fmaxf(mrun, mx * SL2E);
                float corr = exp2f(mrun - mn);
                mrun = mn;
                lrun *= corr;
#pragma unroll
                for (int dt = 0; dt < 4; ++dt)
#pragma unroll
                    for (int r = 0; r < 16; ++r) {
                        float cr = __shfl(corr, (r & 3) + 8 * (r >> 2) + 4 * hh, 64);
                        acc[dt][r] *= cr;
                    }
            }
            float p_[16], psum = 0.f;
#pragma unroll
            for (int r = 0; r < 16; ++r) {
                p_[r] = exp2f(fmaf(sv[r], SL2E, -mrun));
                psum += p_[r];
            }
            lrun += psum;
            uint32_t W[8], X[8];
#pragma unroll
            for (int i = 0; i < 8; ++i)
                asm("v_cvt_pk_bf16_f32 %0, %1, %2"
                    : "=v"(W[i]) : "v"(p_[2 * i]), "v"(p_[2 * i + 1]));
#pragma unroll
            for (int i = 0; i < 8; ++i) X[i] = __shfl_xor(W[i], 32, 64);
            union { uint32_t u[4]; bf16x8 v; } fa, fb;
            fa.u[0] = hh ? X[2] : W[0];  fa.u[1] = hh ? X[3] : W[1];
            fa.u[2] = hh ? W[2] : X[0];  fa.u[3] = hh ? W[3] : X[1];
            fb.u[0] = hh ? X[6] : W[4];  fb.u[1] = hh ? X[7] : W[5];
            fb.u[2] = hh ? W[6] : X[4];  fb.u[3] = hh ? W[7] : X[5];
            paf[0] = fa.v;
            paf[1] = fb.v;
            PV(t);
        }
    };

    STAGE(p0);                                       // prologue
    bf16x8 kR0[8], kR1[8];
    LOADK(kR0, 2 * p0 + par);

    int p = p0;
    for (;;) {
        BODY(p, kR0, kR1);
        if (++p >= pend) break;
        BODY(p, kR1, kR0);
        if (++p >= pend) break;
    }

    // ---- epilogue: merge parities, write unnormalized partial + (m,l) -----
    __syncthreads();                                 // all PV reads done
    float* mb = (float*)Vring;                       // reuse ring as f32 buffer
    if (par == 1) {
        float lf = lrun + __shfl_xor(lrun, 32, 64);
#pragma unroll
        for (int dt = 0; dt < 4; ++dt)
#pragma unroll
            for (int r = 0; r < 16; ++r)
                mb[((g * 4 + dt) * 16 + r) * 64 + l] = acc[dt][r];
        if (hh == 0) { mlbuf[g][0][c31] = mrun; mlbuf[g][1][c31] = lf; }
    }
    __syncthreads();
    if (par == 0) {
        float l0 = lrun + __shfl_xor(lrun, 32, 64);
        float m1 = mlbuf[g][0][c31], l1 = mlbuf[g][1][c31];
        float M  = fmaxf(mrun, m1);
        float f0 = exp2f(mrun - M);
        float f1 = exp2f(m1 - M);
        float Lm = l0 * f0 + l1 * f1;
#pragma unroll
        for (int dt = 0; dt < 4; ++dt)
#pragma unroll
            for (int r = 0; r < 16; ++r) {
                int qr = (r & 3) + 8 * (r >> 2) + 4 * hh;
                float a0 = __shfl(f0, qr, 64), a1 = __shfl(f1, qr, 64);
                float o = acc[dt][r] * a0 + mb[((g * 4 + dt) * 16 + r) * 64 + l] * a1;
                pbuf[(size_t)slot * 8192 + (32 * g + qr) * 128 + dt * 32 + c31] = f2bf(o);
            }
        if (hh == 0) {
            mlg[slot * 128 + 32 * g + c31]      = M;
            mlg[slot * 128 + 64 + 32 * g + c31] = Lm;
        }
    }
}

// ----------------------------------------------- split-K partial merge -> AO
__global__ __launch_bounds__(256) void k_amerge(const uint16_t* __restrict__ pbuf,
                                                const float* __restrict__ mlg,
                                                uint16_t* __restrict__ AOg) {
    const int h = blockIdx.x, qt = blockIdx.y;
    int base = 0;
    for (int q = 31; q > qt; --q) base += (q + 8) >> 3;
    const int nc = (qt + 8) >> 3;
    const int slot0 = h * 80 + base;
    const int tid = threadIdx.x;
    const int row = tid >> 2, dq = (tid & 3) * 32;

    float M = -1e30f;
    for (int ci = 0; ci < nc; ++ci)
        M = fmaxf(M, mlg[(slot0 + ci) * 128 + row]);
    float L = 0.f;
    float o[32];
#pragma unroll
    for (int j = 0; j < 32; ++j) o[j] = 0.f;
    for (int ci = 0; ci < nc; ++ci) {
        int sl = slot0 + ci;
        float wgt = exp2f(mlg[sl * 128 + row] - M);
        L += mlg[sl * 128 + 64 + row] * wgt;
        const u16x8* pv = (const u16x8*)(pbuf + (size_t)sl * 8192 + row * 128 + dq);
#pragma unroll
        for (int jj = 0; jj < 4; ++jj) {
            u16x8 v = pv[jj];
#pragma unroll
            for (int k = 0; k < 8; ++k) o[jj * 8 + k] += bf2f(v[k]) * wgt;
        }
    }
    float inv = 1.f / L;
    const int b = h >> 3, n = h & 7;
    uint16_t* op = AOg + ((size_t)(b * 2048 + qt * 64 + row)) * 1024 + n * 128 + dq;
#pragma unroll
    for (int jj = 0; jj < 4; ++jj) {
        u16x8 v;
#pragma unroll
        for (int k = 0; k < 8; ++k) v[k] = f2bf(o[jj * 8 + k] * inv);
        ((u16x8*)op)[jj] = v;
    }
}

// ------------------------------------------------------- blade mixing epilogue
__global__ __launch_bounds__(256) void k_mix(const float* __restrict__ out,
                                             const float* __restrict__ alpha,
                                             float* __restrict__ fin) {
    constexpr int SI[42] = {1,1,1,1,1,1, 2,2,2,2,2,2, 3,3,3,3,3,3, 4,4,4,4,4,4,
                            5,5,5,5,5,5, 6,6,6,6,6,6, 7,7,7,7,7,7};
    constexpr int SJ[42] = {2,3,4,5,6,7, 1,3,4,5,6,7, 1,2,4,5,6,7, 1,2,3,5,6,7,
                            1,2,3,4,6,7, 1,2,3,4,5,7, 1,2,3,4,5,6};
    constexpr int TG[42] = {4,5,2,3,7,6, 4,6,1,7,3,5, 5,6,7,1,2,4, 2,1,7,6,5,3,
                            3,7,1,6,4,2, 7,3,2,5,4,1, 6,5,4,3,2,1};
    constexpr float SG[42] = {+1,+1,+1,+1,+1,+1, -1,+1,-1,-1,+1,-1, -1,-1,+1,-1,-1,+1,
                              -1,+1,+1,-1,+1,-1, -1,-1,+1,+1,-1,+1, +1,-1,+1,-1,+1,-1,
                              +1,-1,+1,-1,+1,-1};
    int idx = blockIdx.x * 256 + threadIdx.x;        // B*T * D
    int d = idx & 127, bt = idx >> 7;
    size_t base = (size_t)bt * 1024 + d;
    float o[8], r[8];
#pragma unroll
    for (int hh = 0; hh < 8; ++hh) { o[hh] = out[base + hh * 128]; r[hh] = o[hh]; }
#pragma unroll
    for (int p = 0; p < 42; ++p)
        r[TG[p]] += alpha[SI[p] * 8 + SJ[p]] * SG[p] * o[SI[p]] * o[SJ[p]];
#pragma unroll
    for (int hh = 0; hh < 8; ++hh) fin[base + hh * 128] = r[hh];
}

// ---------------------------------------------------------------------------
extern "C" void kernel_launch(void* const* d_in, const int* in_sizes, int n_in,
                              void* d_out, int out_size, void* d_ws, size_t ws_size,
                              hipStream_t stream) {
    (void)in_sizes; (void)n_in; (void)out_size; (void)ws_size;
    const float* mv    = (const float*)d_in[0];
    const float* Wqkv  = (const float*)d_in[1];
    const float* Wo    = (const float*)d_in[2];
    const float* alpha = (const float*)d_in[3];
    float* outp = (float*)d_out;
    char* ws = (char*)d_ws;

    // workspace layout (bytes); AO overlays Xbf; pbuf/mlg then outF overlay QKV
    uint16_t* Xbf  = (uint16_t*)(ws + 0);            //  8 MB  [4096][1024]
    uint16_t* Wqt  = (uint16_t*)(ws + 8388608);      //  6 MB  [3072][1024]
    uint16_t* Wot  = (uint16_t*)(ws + 14680064);     //  2 MB  [1024][1024]
    uint16_t* QKV  = (uint16_t*)(ws + 16777216);     // 24 MB  [4096][3072]
    uint16_t* Qr   = (uint16_t*)(ws + 41943040);     //  8 MB  [16][2048][128]
    uint16_t* Kr   = (uint16_t*)(ws + 50331648);     //  8 MB
    uint16_t* Vt   = (uint16_t*)(ws + 58720256);     //  8 MB  [16][128][2048]
    float*    ctab = (float*)(ws + 67108864);        // 0.5 MB
    float*    stab = (float*)(ws + 67633152);        // 0.5 MB
    uint16_t* AO   = (uint16_t*)(ws + 0);            // overlay (X dead after GEMM1)
    uint16_t* pbuf = (uint16_t*)(ws + 16777216);     // 21 MB partials (QKV dead)
    float*    mlg  = (float*)(ws + 37748736);        // 0.65 MB m/l partials
    float*    outF = (float*)(ws + 16777216);        // overlay (pbuf dead after merge)

    k_cast  <<<4096, 256, 0, stream>>>(mv, Xbf, 4096 * 1024);
    k_wtrans<<<dim3(48, 16), 256, 0, stream>>>(Wqkv, Wqt, 1024, 3072);
    k_wtrans<<<dim3(16, 16), 256, 0, stream>>>(Wo, Wot, 1024, 1024);
    k_tab   <<<512, 256, 0, stream>>>(ctab, stab);
    k_gemm<uint16_t><<<dim3(24, 32), 256, 0, stream>>>(Xbf, Wqt, QKV, 4096, 3072, 1024);
    k_rope  <<<8192, 256, 0, stream>>>(QKV, ctab, stab, Qr, Kr);
    k_vtrans<<<dim3(2, 32, 16), 256, 0, stream>>>(QKV, Vt);
    k_attn  <<<dim3(16, 80), 256, 0, stream>>>(Qr, Kr, Vt, pbuf, mlg);
    k_amerge<<<dim3(16, 32), 256, 0, stream>>>(pbuf, mlg, AO);
    k_gemm<float><<<dim3(8, 32), 256, 0, stream>>>(AO, Wot, outF, 4096, 1024, 1024);
    k_mix   <<<2048, 256, 0, stream>>>(outF, alpha, outp);
}

// Round 7
// 171.465 us; speedup vs baseline: 1.6919x; 1.6919x over previous
//
#include <hip/hip_runtime.h>
#include <stdint.h>

// ---------------------------------------------------------------------------
// GeometricAttention: x@Wqkv -> RoPE -> causal MHA -> @Wo -> blade mixing
// B=2 T=2048 N=8 D=128, d_model=1024. bf16 MFMA pipeline, fp32 accum.
// ---------------------------------------------------------------------------

typedef __attribute__((ext_vector_type(8)))  __bf16 bf16x8;
typedef __attribute__((ext_vector_type(8)))  uint16_t u16x8;
typedef __attribute__((ext_vector_type(4)))  float  f32x4;
typedef __attribute__((ext_vector_type(16))) float  f32x16;

__device__ __forceinline__ uint16_t f2bf(float f) {
    uint32_t u = __float_as_uint(f);
    u += 0x7FFFu + ((u >> 16) & 1u);           // RNE
    return (uint16_t)(u >> 16);
}
__device__ __forceinline__ float bf2f(uint16_t h) {
    return __uint_as_float(((uint32_t)h) << 16);
}

__device__ __forceinline__ void gload_lds16(const void* g, void* l) {
    __builtin_amdgcn_global_load_lds(
        (__attribute__((address_space(1))) void*)g,
        (__attribute__((address_space(3))) void*)l, 16, 0, 0);
}

__device__ __forceinline__ void store_out(uint16_t* p, float v) { *p = f2bf(v); }
__device__ __forceinline__ void store_out(float* p, float v)    { *p = v; }

// ---------------------------------------------------------------- cast fp32->bf16
__global__ __launch_bounds__(256) void k_cast(const float* __restrict__ in,
                                              uint16_t* __restrict__ out, int n) {
    int i = blockIdx.x * 256 + threadIdx.x;          // one float4 per thread
    if (i * 4 >= n) return;
    float4 v = ((const float4*)in)[i];
    ushort4 o = make_ushort4(f2bf(v.x), f2bf(v.y), f2bf(v.z), f2bf(v.w));
    ((ushort4*)out)[i] = o;
}

// ------------------------------------------------- transpose W [K][N] -> Wt [N][K] bf16
__global__ __launch_bounds__(256) void k_wtrans(const float* __restrict__ W,
                                                uint16_t* __restrict__ Wt,
                                                int K, int N) {
    __shared__ uint16_t tile[64][65];
    const int k0 = blockIdx.y * 64, n0 = blockIdx.x * 64;
    const int c = threadIdx.x & 63, r4 = threadIdx.x >> 6;
#pragma unroll
    for (int i = 0; i < 16; ++i) {
        int r = r4 + i * 4;
        tile[r][c] = f2bf(W[(size_t)(k0 + r) * N + n0 + c]);
    }
    __syncthreads();
#pragma unroll
    for (int i = 0; i < 16; ++i) {
        int r = r4 + i * 4;
        Wt[(size_t)(n0 + r) * K + k0 + c] = tile[c][r];
    }
}

// ---------------------------------------------------------------- RoPE tables
__global__ __launch_bounds__(256) void k_tab(float* __restrict__ ct,
                                             float* __restrict__ st) {
    int i = blockIdx.x * 256 + threadIdx.x;          // 2048*64
    int t = i >> 6, f = i & 63;
    float inv = expf(-(float)f * 0.14391156830441f); // ln(10000)/64
    float ang = (float)t * inv;
    ct[i] = cosf(ang);
    st[i] = sinf(ang);
}

// ------------------------------------------------------- m97-style bf16 GEMM
// C[M][N] = A[M][K] * Bt[N][K]^T ; 128x128 tile, BK=32, 4 waves
template <typename OutT>
__global__ __launch_bounds__(256) void k_gemm(const uint16_t* __restrict__ A,
                                              const uint16_t* __restrict__ Bt,
                                              OutT* __restrict__ C,
                                              int M, int N, int K) {
    __shared__ uint16_t Atile[128 * 32];
    __shared__ uint16_t Btile[128 * 32];
    const int m0 = blockIdx.y << 7, n0 = blockIdx.x << 7;
    const int tid = threadIdx.x;
    const int l = tid & 63, w = tid >> 6;
    const int lr = l & 15, lg = l >> 4;
    const int wm = (w >> 1) << 6, wn = (w & 1) << 6;

    f32x4 acc[4][4];
#pragma unroll
    for (int i = 0; i < 4; ++i)
#pragma unroll
        for (int j = 0; j < 4; ++j) acc[i][j] = (f32x4){0.f, 0.f, 0.f, 0.f};

    const int nk = K >> 5;
    for (int kt = 0; kt < nk; ++kt) {
        const int k0 = kt << 5;
        __syncthreads();
#pragma unroll
        for (int c = 0; c < 4; ++c) {
            int idx = c * 256 + tid;                 // 0..1023, wave-contiguous
            if (idx < 512) {
                int r = idx >> 2, kc = (idx & 3) << 3;
                gload_lds16(A + (size_t)(m0 + r) * K + k0 + kc, &Atile[idx * 8]);
            } else {
                int i2 = idx - 512;
                int r = i2 >> 2, kc = (i2 & 3) << 3;
                gload_lds16(Bt + (size_t)(n0 + r) * K + k0 + kc, &Btile[i2 * 8]);
            }
        }
        __syncthreads();
        bf16x8 af[4], bfv[4];
#pragma unroll
        for (int i = 0; i < 4; ++i) {
            af[i]  = *(const bf16x8*)(&Atile[(wm + i * 16 + lr) * 32 + lg * 8]);
            bfv[i] = *(const bf16x8*)(&Btile[(wn + i * 16 + lr) * 32 + lg * 8]);
        }
#pragma unroll
        for (int mi = 0; mi < 4; ++mi)
#pragma unroll
            for (int ni = 0; ni < 4; ++ni)
                acc[mi][ni] = __builtin_amdgcn_mfma_f32_16x16x32_bf16(
                    af[mi], bfv[ni], acc[mi][ni], 0, 0, 0);
    }
    // C/D layout: col = lane&15, row = (lane>>4)*4 + reg   [m89-verified]
#pragma unroll
    for (int mi = 0; mi < 4; ++mi)
#pragma unroll
        for (int ni = 0; ni < 4; ++ni)
#pragma unroll
            for (int r = 0; r < 4; ++r) {
                int row = m0 + wm + mi * 16 + lg * 4 + r;
                int col = n0 + wn + ni * 16 + lr;
                store_out(&C[(size_t)row * N + col], acc[mi][ni][r]);
            }
}

// ------------------------------------------- RoPE apply: QKV -> Q,K [h][T][D]
__global__ __launch_bounds__(256) void k_rope(const uint16_t* __restrict__ qkv,
                                              const float* __restrict__ ct,
                                              const float* __restrict__ st,
                                              uint16_t* __restrict__ Qo,
                                              uint16_t* __restrict__ Ko) {
    int idx = blockIdx.x * 256 + threadIdx.x;        // B*T*N*64 pairs
    int d  = idx & 63;
    int n  = (idx >> 6) & 7;
    int bt = idx >> 9;
    int t  = bt & 2047, b = bt >> 11;
    float c = ct[t * 64 + d], s = st[t * 64 + d];
    size_t base = (size_t)bt * 3072 + n * 128 + d;
    float q1 = bf2f(qkv[base]),        q2 = bf2f(qkv[base + 64]);
    float k1 = bf2f(qkv[base + 1024]), k2 = bf2f(qkv[base + 1024 + 64]);
    size_t ob = ((size_t)(b * 8 + n) * 2048 + t) * 128 + d;
    Qo[ob]      = f2bf(q1 * c - q2 * s);
    Qo[ob + 64] = f2bf(q2 * c + q1 * s);
    Ko[ob]      = f2bf(k1 * c - k2 * s);
    Ko[ob + 64] = f2bf(k2 * c + k1 * s);
}

// -------------------------------------- V transpose: QKV v-part -> Vt [h][D][T]
__global__ __launch_bounds__(256) void k_vtrans(const uint16_t* __restrict__ qkv,
                                                uint16_t* __restrict__ Vt) {
    __shared__ uint16_t tile[64][65];
    const int h = blockIdx.z, b = h >> 3, n = h & 7;
    const int t0 = blockIdx.y * 64, d0 = blockIdx.x * 64;
    const int c = threadIdx.x & 63, r4 = threadIdx.x >> 6;
#pragma unroll
    for (int i = 0; i < 16; ++i) {
        int r = r4 + i * 4;                          // t offset
        tile[r][c] = qkv[(size_t)(b * 2048 + t0 + r) * 3072 + 2048 + n * 128 + d0 + c];
    }
    __syncthreads();
#pragma unroll
    for (int i = 0; i < 16; ++i) {
        int r = r4 + i * 4;                          // d offset
        Vt[((size_t)h * 128 + d0 + r) * 2048 + t0 + c] = tile[c][r];
    }
}

// --------------------------------------------------- causal flash attention
// R7 = R6 structure with the launch-bounds fix. R6's __launch_bounds__(256,4)
// capped VGPRs at ~128 (<190 needed) -> full scratch spill: FETCH 244MB,
// WRITE 333MB, 193us. (256,2) is the R5-proven budget (124 VGPR + AGPR acc,
// zero spill); VGPR-capped occupancy = 2 blocks/CU x 4 waves = 2 waves/SIMD,
// SUSTAINED via 1280 uniform split-K chunks vs 512 residency slots.
// Split-K: block = chunk of <=8 bodies (body = 64 k = two 32-k parity tiles)
// of one q-tile; heavy chunks dispatched first. K direct global->reg; V in a
// 4-slot LDS ring (global_load_lds, linear dest, inverse-swizzled source).
// Per body: {vmcnt(0); barrier; STAGE(p+1)+LOADK(next); QK; softmax->paf
// in-reg (T12); PV}. Partials (O bf16, m/l f32) merged by k_amerge.
// Lane maps (m74/m101): A row=l&31,k=8h+e; B col=l&31; C col=l&31,
// row=(r&3)+8(r>>2)+4h.
__global__ __launch_bounds__(256, 2) void k_attn(const uint16_t* __restrict__ Qg,
                                                 const uint16_t* __restrict__ Kg,
                                                 const uint16_t* __restrict__ Vtg,
                                                 uint16_t* __restrict__ pbuf,
                                                 float* __restrict__ mlg) {
    __shared__ char  Vring[4 * 8192];                // 4 V tiles (32k x 128d)
    __shared__ float mlbuf[2][2][32];

    const int h = blockIdx.x;
    int s = blockIdx.y, qt = 31, ci = 0;             // slot -> (qt, ci), qt desc
    for (int q = 31; q >= 0; --q) {
        int nc = (q + 8) >> 3;
        if (s < nc) { qt = q; ci = s; break; }
        s -= nc;
    }
    const int slot = h * 80 + blockIdx.y;            // partial-storage index
    const int p0   = ci * 8;
    const int pend = min(p0 + 8, qt + 1);
    const int q0 = qt * 64;
    const int tid = threadIdx.x;
    const int l = tid & 63, w = tid >> 6;
    const int g = w & 1, par = w >> 1;               // q-group, k-parity
    const int c31 = l & 31, hh = l >> 5;
    const int lastT = 2 * qt + g;                    // diagonal tile for group g
    const size_t headTD = (size_t)h * (2048 * 128);
    const uint16_t* Kh = Kg + headTD;
    const uint16_t* Vh = Vtg + headTD;

    // Q in registers: B-frag col=q=c31, contraction d = 16t + 8hh + e
    bf16x8 qB[8];
    {
        const uint16_t* qp = Qg + headTD + (size_t)(q0 + 32 * g + c31) * 128 + hh * 8;
#pragma unroll
        for (int t = 0; t < 8; ++t) qB[t] = *(const bf16x8*)(qp + t * 16);
    }

    f32x16 acc[4];                                   // O[q-rows][dt*32+c31]
#pragma unroll
    for (int dt = 0; dt < 4; ++dt)
#pragma unroll
        for (int r = 0; r < 16; ++r) acc[dt][r] = 0.f;
    float mrun = -1e30f, lrun = 0.f;                 // per-lane row q=c31 (hh-split)
    bf16x8 paf[2];

    const float SL2E = 0.08838834764831845f * 1.4426950408889634f; // scale*log2e

    auto LOADK = [&](bf16x8* d, int t) {             // A-frags: K[t*32+c31][16i+8hh+e]
        const uint16_t* kp = Kh + (size_t)(t * 32 + c31) * 128 + hh * 8;
#pragma unroll
        for (int i = 0; i < 8; ++i) d[i] = *(const bf16x8*)(kp + i * 16);
    };
    auto STAGE = [&](int pp) {                       // stage V tiles 2pp, 2pp+1
#pragma unroll
        for (int i = 0; i < 4; ++i) {
            int u2 = i * 256 + tid;
            int tt = 2 * pp + (u2 >> 9);
            int uu = u2 & 511;
            int d  = uu >> 2, c16 = uu & 3;
            gload_lds16(Vh + (size_t)d * 2048 + tt * 32 + (c16 ^ ((d >> 1) & 3)) * 8,
                        Vring + (tt & 3) * 8192 + d * 64 + c16 * 16);
        }
    };
    auto PV = [&](int t) {                           // O += P V for tile t
        const char* Vb = Vring + (t & 3) * 8192;
        __builtin_amdgcn_s_setprio(1);
#pragma unroll
        for (int j = 0; j < 2; ++j)
#pragma unroll
            for (int dt = 0; dt < 4; ++dt) {
                int dr = dt * 32 + c31;
                bf16x8 vf = *(const bf16x8*)(Vb + dr * 64 +
                             ((j * 32 + hh * 16) ^ (((dr >> 1) & 3) << 4)));
                acc[dt] = __builtin_amdgcn_mfma_f32_32x32x16_bf16(paf[j], vf, acc[dt], 0, 0, 0);
            }
        __builtin_amdgcn_s_setprio(0);
    };
    auto BODY = [&](int p, bf16x8* kc, bf16x8* kn) {
        asm volatile("s_waitcnt vmcnt(0)" ::: "memory"); // prev body's loads done
        __builtin_amdgcn_s_barrier();
        __builtin_amdgcn_sched_barrier(0);
        if (p + 1 < pend) { STAGE(p + 1); LOADK(kn, 2 * (p + 1) + par); }
        const int t = 2 * p + par;
        if (t <= lastT) {
            f32x16 sv;
#pragma unroll
            for (int r = 0; r < 16; ++r) sv[r] = 0.f;
            __builtin_amdgcn_s_setprio(1);
#pragma unroll
            for (int i = 0; i < 8; ++i)
                sv = __builtin_amdgcn_mfma_f32_32x32x16_bf16(kc[i], qB[i], sv, 0, 0, 0);
            __builtin_amdgcn_s_setprio(0);
            if (t == lastT) {                        // diagonal tile mask
#pragma unroll
                for (int r = 0; r < 16; ++r)
                    if ((r & 3) + 8 * (r >> 2) + 4 * hh > c31) sv[r] = -1e30f;
            }
            float pml = sv[0];
#pragma unroll
            for (int r = 1; r < 16; ++r) pml = fmaxf(pml, sv[r]);
            if (!__all(pml * SL2E <= mrun + 11.f)) { // rare: true max + rescale
                float mx = fmaxf(pml, __shfl_xor(pml, 32, 64));
                float mn = fmaxf(mrun, mx * SL2E);
                float corr = exp2f(mrun - mn);
                mrun = mn;
                lrun *= corr;
#pragma unroll
                for (int dt = 0; dt < 4; ++dt)
#pragma unroll
                    for (int r = 0; r < 16; ++r) {
                        float cr = __shfl(corr, (r & 3) + 8 * (r >> 2) + 4 * hh, 64);
                        acc[dt][r] *= cr;
                    }
            }
            float p_[16], psum = 0.f;
#pragma unroll
            for (int r = 0; r < 16; ++r) {
                p_[r] = exp2f(fmaf(sv[r], SL2E, -mrun));
                psum += p_[r];
            }
            lrun += psum;
            uint32_t W[8], X[8];
#pragma unroll
            for (int i = 0; i < 8; ++i)
                asm("v_cvt_pk_bf16_f32 %0, %1, %2"
                    : "=v"(W[i]) : "v"(p_[2 * i]), "v"(p_[2 * i + 1]));
#pragma unroll
            for (int i = 0; i < 8; ++i) X[i] = __shfl_xor(W[i], 32, 64);
            union { uint32_t u[4]; bf16x8 v; } fa, fb;
            fa.u[0] = hh ? X[2] : W[0];  fa.u[1] = hh ? X[3] : W[1];
            fa.u[2] = hh ? W[2] : X[0];  fa.u[3] = hh ? W[3] : X[1];
            fb.u[0] = hh ? X[6] : W[4];  fb.u[1] = hh ? X[7] : W[5];
            fb.u[2] = hh ? W[6] : X[4];  fb.u[3] = hh ? W[7] : X[5];
            paf[0] = fa.v;
            paf[1] = fb.v;
            PV(t);
        }
    };

    STAGE(p0);                                       // prologue
    bf16x8 kR0[8], kR1[8];
    LOADK(kR0, 2 * p0 + par);

    int p = p0;
    for (;;) {
        BODY(p, kR0, kR1);
        if (++p >= pend) break;
        BODY(p, kR1, kR0);
        if (++p >= pend) break;
    }

    // ---- epilogue: merge parities, write unnormalized partial + (m,l) -----
    __syncthreads();                                 // all PV reads done
    float* mb = (float*)Vring;                       // reuse ring as f32 buffer
    if (par == 1) {
        float lf = lrun + __shfl_xor(lrun, 32, 64);
#pragma unroll
        for (int dt = 0; dt < 4; ++dt)
#pragma unroll
            for (int r = 0; r < 16; ++r)
                mb[((g * 4 + dt) * 16 + r) * 64 + l] = acc[dt][r];
        if (hh == 0) { mlbuf[g][0][c31] = mrun; mlbuf[g][1][c31] = lf; }
    }
    __syncthreads();
    if (par == 0) {
        float l0 = lrun + __shfl_xor(lrun, 32, 64);
        float m1 = mlbuf[g][0][c31], l1 = mlbuf[g][1][c31];
        float M  = fmaxf(mrun, m1);
        float f0 = exp2f(mrun - M);
        float f1 = exp2f(m1 - M);
        float Lm = l0 * f0 + l1 * f1;
#pragma unroll
        for (int dt = 0; dt < 4; ++dt)
#pragma unroll
            for (int r = 0; r < 16; ++r) {
                int qr = (r & 3) + 8 * (r >> 2) + 4 * hh;
                float a0 = __shfl(f0, qr, 64), a1 = __shfl(f1, qr, 64);
                float o = acc[dt][r] * a0 + mb[((g * 4 + dt) * 16 + r) * 64 + l] * a1;
                pbuf[(size_t)slot * 8192 + (32 * g + qr) * 128 + dt * 32 + c31] = f2bf(o);
            }
        if (hh == 0) {
            mlg[slot * 128 + 32 * g + c31]      = M;
            mlg[slot * 128 + 64 + 32 * g + c31] = Lm;
        }
    }
}

// ----------------------------------------------- split-K partial merge -> AO
__global__ __launch_bounds__(256) void k_amerge(const uint16_t* __restrict__ pbuf,
                                                const float* __restrict__ mlg,
                                                uint16_t* __restrict__ AOg) {
    const int h = blockIdx.x, qt = blockIdx.y;
    int base = 0;
    for (int q = 31; q > qt; --q) base += (q + 8) >> 3;
    const int nc = (qt + 8) >> 3;
    const int slot0 = h * 80 + base;
    const int tid = threadIdx.x;
    const int row = tid >> 2, dq = (tid & 3) * 32;

    float M = -1e30f;
    for (int ci = 0; ci < nc; ++ci)
        M = fmaxf(M, mlg[(slot0 + ci) * 128 + row]);
    float L = 0.f;
    float o[32];
#pragma unroll
    for (int j = 0; j < 32; ++j) o[j] = 0.f;
    for (int ci = 0; ci < nc; ++ci) {
        int sl = slot0 + ci;
        float wgt = exp2f(mlg[sl * 128 + row] - M);
        L += mlg[sl * 128 + 64 + row] * wgt;
        const u16x8* pv = (const u16x8*)(pbuf + (size_t)sl * 8192 + row * 128 + dq);
#pragma unroll
        for (int jj = 0; jj < 4; ++jj) {
            u16x8 v = pv[jj];
#pragma unroll
            for (int k = 0; k < 8; ++k) o[jj * 8 + k] += bf2f(v[k]) * wgt;
        }
    }
    float inv = 1.f / L;
    const int b = h >> 3, n = h & 7;
    uint16_t* op = AOg + ((size_t)(b * 2048 + qt * 64 + row)) * 1024 + n * 128 + dq;
#pragma unroll
    for (int jj = 0; jj < 4; ++jj) {
        u16x8 v;
#pragma unroll
        for (int k = 0; k < 8; ++k) v[k] = f2bf(o[jj * 8 + k] * inv);
        ((u16x8*)op)[jj] = v;
    }
}

// ------------------------------------------------------- blade mixing epilogue
__global__ __launch_bounds__(256) void k_mix(const float* __restrict__ out,
                                             const float* __restrict__ alpha,
                                             float* __restrict__ fin) {
    constexpr int SI[42] = {1,1,1,1,1,1, 2,2,2,2,2,2, 3,3,3,3,3,3, 4,4,4,4,4,4,
                            5,5,5,5,5,5, 6,6,6,6,6,6, 7,7,7,7,7,7};
    constexpr int SJ[42] = {2,3,4,5,6,7, 1,3,4,5,6,7, 1,2,4,5,6,7, 1,2,3,5,6,7,
                            1,2,3,4,6,7, 1,2,3,4,5,7, 1,2,3,4,5,6};
    constexpr int TG[42] = {4,5,2,3,7,6, 4,6,1,7,3,5, 5,6,7,1,2,4, 2,1,7,6,5,3,
                            3,7,1,6,4,2, 7,3,2,5,4,1, 6,5,4,3,2,1};
    constexpr float SG[42] = {+1,+1,+1,+1,+1,+1, -1,+1,-1,-1,+1,-1, -1,-1,+1,-1,-1,+1,
                              -1,+1,+1,-1,+1,-1, -1,-1,+1,+1,-1,+1, +1,-1,+1,-1,+1,-1,
                              +1,-1,+1,-1,+1,-1};
    int idx = blockIdx.x * 256 + threadIdx.x;        // B*T * D
    int d = idx & 127, bt = idx >> 7;
    size_t base = (size_t)bt * 1024 + d;
    float o[8], r[8];
#pragma unroll
    for (int hh = 0; hh < 8; ++hh) { o[hh] = out[base + hh * 128]; r[hh] = o[hh]; }
#pragma unroll
    for (int p = 0; p < 42; ++p)
        r[TG[p]] += alpha[SI[p] * 8 + SJ[p]] * SG[p] * o[SI[p]] * o[SJ[p]];
#pragma unroll
    for (int hh = 0; hh < 8; ++hh) fin[base + hh * 128] = r[hh];
}

// ---------------------------------------------------------------------------
extern "C" void kernel_launch(void* const* d_in, const int* in_sizes, int n_in,
                              void* d_out, int out_size, void* d_ws, size_t ws_size,
                              hipStream_t stream) {
    (void)in_sizes; (void)n_in; (void)out_size; (void)ws_size;
    const float* mv    = (const float*)d_in[0];
    const float* Wqkv  = (const float*)d_in[1];
    const float* Wo    = (const float*)d_in[2];
    const float* alpha = (const float*)d_in[3];
    float* outp = (float*)d_out;
    char* ws = (char*)d_ws;

    // workspace layout (bytes); AO overlays Xbf; pbuf/mlg then outF overlay QKV
    uint16_t* Xbf  = (uint16_t*)(ws + 0);            //  8 MB  [4096][1024]
    uint16_t* Wqt  = (uint16_t*)(ws + 8388608);      //  6 MB  [3072][1024]
    uint16_t* Wot  = (uint16_t*)(ws + 14680064);     //  2 MB  [1024][1024]
    uint16_t* QKV  = (uint16_t*)(ws + 16777216);     // 24 MB  [4096][3072]
    uint16_t* Qr   = (uint16_t*)(ws + 41943040);     //  8 MB  [16][2048][128]
    uint16_t* Kr   = (uint16_t*)(ws + 50331648);     //  8 MB
    uint16_t* Vt   = (uint16_t*)(ws + 58720256);     //  8 MB  [16][128][2048]
    float*    ctab = (float*)(ws + 67108864);        // 0.5 MB
    float*    stab = (float*)(ws + 67633152);        // 0.5 MB
    uint16_t* AO   = (uint16_t*)(ws + 0);            // overlay (X dead after GEMM1)
    uint16_t* pbuf = (uint16_t*)(ws + 16777216);     // 21 MB partials (QKV dead)
    float*    mlg  = (float*)(ws + 37748736);        // 0.65 MB m/l partials
    float*    outF = (float*)(ws + 16777216);        // overlay (pbuf dead after merge)

    k_cast  <<<4096, 256, 0, stream>>>(mv, Xbf, 4096 * 1024);
    k_wtrans<<<dim3(48, 16), 256, 0, stream>>>(Wqkv, Wqt, 1024, 3072);
    k_wtrans<<<dim3(16, 16), 256, 0, stream>>>(Wo, Wot, 1024, 1024);
    k_tab   <<<512, 256, 0, stream>>>(ctab, stab);
    k_gemm<uint16_t><<<dim3(24, 32), 256, 0, stream>>>(Xbf, Wqt, QKV, 4096, 3072, 1024);
    k_rope  <<<8192, 256, 0, stream>>>(QKV, ctab, stab, Qr, Kr);
    k_vtrans<<<dim3(2, 32, 16), 256, 0, stream>>>(QKV, Vt);
    k_attn  <<<dim3(16, 80), 256, 0, stream>>>(Qr, Kr, Vt, pbuf, mlg);
    k_amerge<<<dim3(16, 32), 256, 0, stream>>>(pbuf, mlg, AO);
    k_gemm<float><<<dim3(8, 32), 256, 0, stream>>>(AO, Wot, outF, 4096, 1024, 1024);
    k_mix   <<<2048, 256, 0, stream>>>(outF, alpha, outp);
}

// Round 9
// 146.377 us; speedup vs baseline: 1.9819x; 1.1714x over previous
//
#include <hip/hip_runtime.h>
#include <stdint.h>

// ---------------------------------------------------------------------------
// GeometricAttention: x@Wqkv -> RoPE -> causal MHA -> @Wo -> blade mixing
// B=2 T=2048 N=8 D=128, d_model=1024. bf16 MFMA pipeline, fp32 accum.
// ---------------------------------------------------------------------------

typedef __attribute__((ext_vector_type(8)))  __bf16 bf16x8;
typedef __attribute__((ext_vector_type(4)))  float  f32x4;

__device__ __forceinline__ uint16_t f2bf(float f) {
    uint32_t u = __float_as_uint(f);
    u += 0x7FFFu + ((u >> 16) & 1u);           // RNE
    return (uint16_t)(u >> 16);
}
__device__ __forceinline__ float bf2f(uint16_t h) {
    return __uint_as_float(((uint32_t)h) << 16);
}

__device__ __forceinline__ void gload_lds16(const void* g, void* l) {
    __builtin_amdgcn_global_load_lds(
        (__attribute__((address_space(1))) void*)g,
        (__attribute__((address_space(3))) void*)l, 16, 0, 0);
}

__device__ __forceinline__ void store_out(uint16_t* p, float v) { *p = f2bf(v); }
__device__ __forceinline__ void store_out(float* p, float v)    { *p = v; }

// ---------------------------------------------------------------- cast fp32->bf16
__global__ __launch_bounds__(256) void k_cast(const float* __restrict__ in,
                                              uint16_t* __restrict__ out, int n) {
    int i = blockIdx.x * 256 + threadIdx.x;          // one float4 per thread
    if (i * 4 >= n) return;
    float4 v = ((const float4*)in)[i];
    ushort4 o = make_ushort4(f2bf(v.x), f2bf(v.y), f2bf(v.z), f2bf(v.w));
    ((ushort4*)out)[i] = o;
}

// ------------------------------------------------- transpose W [K][N] -> Wt [N][K] bf16
__global__ __launch_bounds__(256) void k_wtrans(const float* __restrict__ W,
                                                uint16_t* __restrict__ Wt,
                                                int K, int N) {
    __shared__ uint16_t tile[64][65];
    const int k0 = blockIdx.y * 64, n0 = blockIdx.x * 64;
    const int c = threadIdx.x & 63, r4 = threadIdx.x >> 6;
#pragma unroll
    for (int i = 0; i < 16; ++i) {
        int r = r4 + i * 4;
        tile[r][c] = f2bf(W[(size_t)(k0 + r) * N + n0 + c]);
    }
    __syncthreads();
#pragma unroll
    for (int i = 0; i < 16; ++i) {
        int r = r4 + i * 4;
        Wt[(size_t)(n0 + r) * K + k0 + c] = tile[c][r];
    }
}

// ---------------------------------------------------------------- RoPE tables
__global__ __launch_bounds__(256) void k_tab(float* __restrict__ ct,
                                             float* __restrict__ st) {
    int i = blockIdx.x * 256 + threadIdx.x;          // 2048*64
    int t = i >> 6, f = i & 63;
    float inv = expf(-(float)f * 0.14391156830441f); // ln(10000)/64
    float ang = (float)t * inv;
    ct[i] = cosf(ang);
    st[i] = sinf(ang);
}

// ------------------------------------------------------- m97-style bf16 GEMM
// C[M][N] = A[M][K] * Bt[N][K]^T ; 128x128 tile, BK=32, 4 waves
template <typename OutT>
__global__ __launch_bounds__(256) void k_gemm(const uint16_t* __restrict__ A,
                                              const uint16_t* __restrict__ Bt,
                                              OutT* __restrict__ C,
                                              int M, int N, int K) {
    __shared__ uint16_t Atile[128 * 32];
    __shared__ uint16_t Btile[128 * 32];
    const int m0 = blockIdx.y << 7, n0 = blockIdx.x << 7;
    const int tid = threadIdx.x;
    const int l = tid & 63, w = tid >> 6;
    const int lr = l & 15, lg = l >> 4;
    const int wm = (w >> 1) << 6, wn = (w & 1) << 6;

    f32x4 acc[4][4];
#pragma unroll
    for (int i = 0; i < 4; ++i)
#pragma unroll
        for (int j = 0; j < 4; ++j) acc[i][j] = (f32x4){0.f, 0.f, 0.f, 0.f};

    const int nk = K >> 5;
    for (int kt = 0; kt < nk; ++kt) {
        const int k0 = kt << 5;
        __syncthreads();
#pragma unroll
        for (int c = 0; c < 4; ++c) {
            int idx = c * 256 + tid;                 // 0..1023, wave-contiguous
            if (idx < 512) {
                int r = idx >> 2, kc = (idx & 3) << 3;
                gload_lds16(A + (size_t)(m0 + r) * K + k0 + kc, &Atile[idx * 8]);
            } else {
                int i2 = idx - 512;
                int r = i2 >> 2, kc = (i2 & 3) << 3;
                gload_lds16(Bt + (size_t)(n0 + r) * K + k0 + kc, &Btile[i2 * 8]);
            }
        }
        __syncthreads();
        bf16x8 af[4], bfv[4];
#pragma unroll
        for (int i = 0; i < 4; ++i) {
            af[i]  = *(const bf16x8*)(&Atile[(wm + i * 16 + lr) * 32 + lg * 8]);
            bfv[i] = *(const bf16x8*)(&Btile[(wn + i * 16 + lr) * 32 + lg * 8]);
        }
#pragma unroll
        for (int mi = 0; mi < 4; ++mi)
#pragma unroll
            for (int ni = 0; ni < 4; ++ni)
                acc[mi][ni] = __builtin_amdgcn_mfma_f32_16x16x32_bf16(
                    af[mi], bfv[ni], acc[mi][ni], 0, 0, 0);
    }
    // C/D layout: col = lane&15, row = (lane>>4)*4 + reg   [m89-verified]
#pragma unroll
    for (int mi = 0; mi < 4; ++mi)
#pragma unroll
        for (int ni = 0; ni < 4; ++ni)
#pragma unroll
            for (int r = 0; r < 4; ++r) {
                int row = m0 + wm + mi * 16 + lg * 4 + r;
                int col = n0 + wn + ni * 16 + lr;
                store_out(&C[(size_t)row * N + col], acc[mi][ni][r]);
            }
}

// -------------------------------------- split-K out-proj GEMM (occupancy fix)
// M=4096, N=1024 -> 128^2 tiles give only 256 blocks = 1 block/CU (m102-style
// starvation). Single launch, grid (8,32,2): z = K-half. 512 blocks = 2/CU.
// Halves write C and C + 4M floats (contiguous 32 MB); summed in k_mix.
__global__ __launch_bounds__(256) void k_gemm2s(const uint16_t* __restrict__ A,
                                                const uint16_t* __restrict__ Bt,
                                                float* __restrict__ C) {
    __shared__ uint16_t Atile[128 * 32];
    __shared__ uint16_t Btile[128 * 32];
    const int kz = blockIdx.z;
    A  += (size_t)kz * 512;                          // k-offset within row
    Bt += (size_t)kz * 512;
    C  += (size_t)kz * (4096u * 1024u);              // partial-output buffer
    const int m0 = blockIdx.y << 7, n0 = blockIdx.x << 7;
    const int tid = threadIdx.x;
    const int l = tid & 63, w = tid >> 6;
    const int lr = l & 15, lg = l >> 4;
    const int wm = (w >> 1) << 6, wn = (w & 1) << 6;

    f32x4 acc[4][4];
#pragma unroll
    for (int i = 0; i < 4; ++i)
#pragma unroll
        for (int j = 0; j < 4; ++j) acc[i][j] = (f32x4){0.f, 0.f, 0.f, 0.f};

    for (int kt = 0; kt < 16; ++kt) {                // K_half = 512 = 16 x 32
        const int k0 = kt << 5;
        __syncthreads();
#pragma unroll
        for (int c = 0; c < 4; ++c) {
            int idx = c * 256 + tid;
            if (idx < 512) {
                int r = idx >> 2, kc = (idx & 3) << 3;
                gload_lds16(A + (size_t)(m0 + r) * 1024 + k0 + kc, &Atile[idx * 8]);
            } else {
                int i2 = idx - 512;
                int r = i2 >> 2, kc = (i2 & 3) << 3;
                gload_lds16(Bt + (size_t)(n0 + r) * 1024 + k0 + kc, &Btile[i2 * 8]);
            }
        }
        __syncthreads();
        bf16x8 af[4], bfv[4];
#pragma unroll
        for (int i = 0; i < 4; ++i) {
            af[i]  = *(const bf16x8*)(&Atile[(wm + i * 16 + lr) * 32 + lg * 8]);
            bfv[i] = *(const bf16x8*)(&Btile[(wn + i * 16 + lr) * 32 + lg * 8]);
        }
#pragma unroll
        for (int mi = 0; mi < 4; ++mi)
#pragma unroll
            for (int ni = 0; ni < 4; ++ni)
                acc[mi][ni] = __builtin_amdgcn_mfma_f32_16x16x32_bf16(
                    af[mi], bfv[ni], acc[mi][ni], 0, 0, 0);
    }
#pragma unroll
    for (int mi = 0; mi < 4; ++mi)
#pragma unroll
        for (int ni = 0; ni < 4; ++ni)
#pragma unroll
            for (int r = 0; r < 4; ++r) {
                int row = m0 + wm + mi * 16 + lg * 4 + r;
                int col = n0 + wn + ni * 16 + lr;
                C[(size_t)row * 1024 + col] = acc[mi][ni][r];
            }
}

// ------------------------------------------- RoPE apply: QKV -> Q,K [h][T][D]
__global__ __launch_bounds__(256) void k_rope(const uint16_t* __restrict__ qkv,
                                              const float* __restrict__ ct,
                                              const float* __restrict__ st,
                                              uint16_t* __restrict__ Qo,
                                              uint16_t* __restrict__ Ko) {
    int idx = blockIdx.x * 256 + threadIdx.x;        // B*T*N*64 pairs
    int d  = idx & 63;
    int n  = (idx >> 6) & 7;
    int bt = idx >> 9;
    int t  = bt & 2047, b = bt >> 11;
    float c = ct[t * 64 + d], s = st[t * 64 + d];
    size_t base = (size_t)bt * 3072 + n * 128 + d;
    float q1 = bf2f(qkv[base]),        q2 = bf2f(qkv[base + 64]);
    float k1 = bf2f(qkv[base + 1024]), k2 = bf2f(qkv[base + 1024 + 64]);
    size_t ob = ((size_t)(b * 8 + n) * 2048 + t) * 128 + d;
    Qo[ob]      = f2bf(q1 * c - q2 * s);
    Qo[ob + 64] = f2bf(q2 * c + q1 * s);
    Ko[ob]      = f2bf(k1 * c - k2 * s);
    Ko[ob + 64] = f2bf(k2 * c + k1 * s);
}

// -------------------------------------- V transpose: QKV v-part -> Vt [h][D][T]
__global__ __launch_bounds__(256) void k_vtrans(const uint16_t* __restrict__ qkv,
                                                uint16_t* __restrict__ Vt) {
    __shared__ uint16_t tile[64][65];
    const int h = blockIdx.z, b = h >> 3, n = h & 7;
    const int t0 = blockIdx.y * 64, d0 = blockIdx.x * 64;
    const int c = threadIdx.x & 63, r4 = threadIdx.x >> 6;
#pragma unroll
    for (int i = 0; i < 16; ++i) {
        int r = r4 + i * 4;                          // t offset
        tile[r][c] = qkv[(size_t)(b * 2048 + t0 + r) * 3072 + 2048 + n * 128 + d0 + c];
    }
    __syncthreads();
#pragma unroll
    for (int i = 0; i < 16; ++i) {
        int r = r4 + i * 4;                          // d offset
        Vt[((size_t)h * 128 + d0 + r) * 2048 + t0 + c] = tile[c][r];
    }
}

// --------------------------------------------------- causal flash attention
// R3-proven kernel (58 us): swapped QK^T (S^T = mfma(K,Q)) so each lane holds
// P[q=lr][16 k] lane-locally; softmax state scalar/lane, common path has NO
// cross-lane ops. P -> LDS as packed b64 (cvt_pk_bf16 pairs), read back as
// swizzled b128 A-frags. K/V double-buffered via global_load_lds (linear
// dest, inverse-swizzled src). Heavy/light block pairing.
__global__ __launch_bounds__(256) void k_attn(const uint16_t* __restrict__ Qg,
                                              const uint16_t* __restrict__ Kg,
                                              const uint16_t* __restrict__ Vtg,
                                              uint16_t* __restrict__ AOg) {
    __shared__ uint16_t Klds[2][64 * 128];           // 16 KB each, XOR-swizzled
    __shared__ uint16_t Vlds[2][128 * 64];           // 16 KB each, XOR-swizzled
    __shared__ uint16_t Plds[4][16 * 64];            // 2 KB per wave, swizzled

    const int bx = blockIdx.x;
    const int h  = bx & 15;
    const int t4 = (bx >> 4) & 15;
    const int qt = (bx < 256) ? (31 - t4) : t4;      // heavy/light pairing
    const int q0 = qt * 64;
    const int tid = threadIdx.x;
    const int l = tid & 63, w = tid >> 6;
    const int lr = l & 15, lg = l >> 4;
    const size_t headTD = (size_t)h * (2048 * 128);
    const uint16_t* Kh = Kg + headTD;
    const uint16_t* Vh = Vtg + headTD;

    bf16x8 qf[4];
    {
        const uint16_t* qp = Qg + headTD + (size_t)(q0 + w * 16 + lr) * 128 + lg * 8;
#pragma unroll
        for (int kc = 0; kc < 4; ++kc) qf[kc] = *(const bf16x8*)(qp + kc * 32);
    }

    f32x4 accO[8];
#pragma unroll
    for (int i = 0; i < 8; ++i) accO[i] = (f32x4){0.f, 0.f, 0.f, 0.f};
    float mrun = -1e30f, lrun = 0.f;                 // per-lane row q = lr

    const float SL2E = 0.08838834764831845f * 1.4426950408889634f; // scale*log2e
    const int   swz  = (lr & 7) << 4;                // per-lane swizzle (row=lr)
    uint16_t* Pw = &Plds[w][0];

    auto STAGE = [&](int buf, int k0) {
#pragma unroll
        for (int p = 0; p < 4; ++p) {                // K: 64x128 rows of 256B
            int u = p * 256 + tid;                   // 16B chunk id
            int row = u >> 4;
            int c16 = (u & 15) ^ (row & 7);          // inverse swizzle on SOURCE
            gload_lds16(Kh + (size_t)(k0 + row) * 128 + c16 * 8,
                        (char*)&Klds[buf][0] + u * 16);
        }
#pragma unroll
        for (int p = 0; p < 4; ++p) {                // V: 128x64 rows of 128B
            int u = p * 256 + tid;
            int d = u >> 3;
            int c8 = (u & 7) ^ (d & 7);
            gload_lds16(Vh + (size_t)d * 2048 + k0 + c8 * 8,
                        (char*)&Vlds[buf][0] + u * 16);
        }
    };

    STAGE(0, 0);                                     // prologue

    for (int kt = 0; kt <= qt; ++kt) {
        asm volatile("s_waitcnt vmcnt(0)" ::: "memory"); // tile kt's loads done
        __builtin_amdgcn_s_barrier();
        __builtin_amdgcn_sched_barrier(0);
        if (kt < qt) STAGE((kt + 1) & 1, (kt + 1) * 64); // async prefetch

        const char* Kb = (const char*)&Klds[kt & 1][0];
        const char* Vb = (const char*)&Vlds[kt & 1][0];

        // ---- S^T = K Q^T : lane holds S[q=lr][k = cg*16 + lg*4 + r] ------
        float sv[4][4];
        __builtin_amdgcn_s_setprio(1);
#pragma unroll
        for (int cg = 0; cg < 4; ++cg) {
            f32x4 a = (f32x4){0.f, 0.f, 0.f, 0.f};
#pragma unroll
            for (int kc = 0; kc < 4; ++kc) {
                int kb = (cg * 16 + lr) * 256 + ((kc * 64 + lg * 16) ^ swz);
                bf16x8 kf = *(const bf16x8*)(Kb + kb);
                a = __builtin_amdgcn_mfma_f32_16x16x32_bf16(kf, qf[kc], a, 0, 0, 0);
            }
#pragma unroll
            for (int r = 0; r < 4; ++r) sv[cg][r] = a[r];
        }
        __builtin_amdgcn_s_setprio(0);

        if (kt == qt) {                              // causal mask, diagonal tile
#pragma unroll
            for (int cg = 0; cg < 4; ++cg)
#pragma unroll
                for (int r = 0; r < 4; ++r)
                    if (cg * 16 + lg * 4 + r > w * 16 + lr) sv[cg][r] = -1e30f;
        }

        // ---- defer-max online softmax (lane-local row) -------------------
        float pml = sv[0][0];
#pragma unroll
        for (int cg = 0; cg < 4; ++cg)
#pragma unroll
            for (int r = 0; r < 4; ++r) pml = fmaxf(pml, sv[cg][r]);

        if (!__all(pml * SL2E <= mrun + 11.f)) {     // rare: true max + rescale
            float mx = pml;
            mx = fmaxf(mx, __shfl_xor(mx, 16, 64));
            mx = fmaxf(mx, __shfl_xor(mx, 32, 64));  // full row max (q = lr)
            float mn = fmaxf(mrun, mx * SL2E);
            float corr = exp2f(mrun - mn);
            mrun = mn;
            lrun *= corr;                            // lane-partial sum scales too
            float ca[4];
#pragma unroll
            for (int r = 0; r < 4; ++r)              // corr for accO rows q=lg*4+r
                ca[r] = __shfl(corr, (lg << 4) + lg * 4 + r, 64);
#pragma unroll
            for (int i = 0; i < 8; ++i)
#pragma unroll
                for (int r = 0; r < 4; ++r) accO[i][r] *= ca[r];
        }

        float psum = 0.f;
        float p[4][4];
#pragma unroll
        for (int cg = 0; cg < 4; ++cg)
#pragma unroll
            for (int r = 0; r < 4; ++r) {
                p[cg][r] = exp2f(fmaf(sv[cg][r], SL2E, -mrun));
                psum += p[cg][r];
            }
        lrun += psum;

        // pack P pairs -> b64 LDS writes (row q=lr, k = 16cg+4lg .. +3)
#pragma unroll
        for (int cg = 0; cg < 4; ++cg) {
            uint32_t w0, w1;
            asm("v_cvt_pk_bf16_f32 %0, %1, %2" : "=v"(w0) : "v"(p[cg][0]), "v"(p[cg][1]));
            asm("v_cvt_pk_bf16_f32 %0, %1, %2" : "=v"(w1) : "v"(p[cg][2]), "v"(p[cg][3]));
            uint2 pr; pr.x = w0; pr.y = w1;
            *(uint2*)((char*)Pw + lr * 128 + ((cg * 32 + lg * 8) ^ swz)) = pr;
        }

        asm volatile("" ::: "memory");               // order P stores before reads
        bf16x8 pf[2];
#pragma unroll
        for (int c = 0; c < 2; ++c)
            pf[c] = *(const bf16x8*)((char*)Pw + lr * 128 + ((c * 64 + lg * 16) ^ swz));

        __builtin_amdgcn_s_setprio(1);
#pragma unroll
        for (int ni = 0; ni < 8; ++ni)
#pragma unroll
            for (int c = 0; c < 2; ++c) {
                int vb = (ni * 16 + lr) * 128 + ((c * 64 + lg * 16) ^ swz);
                bf16x8 vf = *(const bf16x8*)(Vb + vb);
                accO[ni] = __builtin_amdgcn_mfma_f32_16x16x32_bf16(pf[c], vf, accO[ni], 0, 0, 0);
            }
        __builtin_amdgcn_s_setprio(0);
    }

    // row sums: reduce lane-partials across the 4 lg lanes, then redistribute
    float lsum = lrun;
    lsum += __shfl_xor(lsum, 16, 64);
    lsum += __shfl_xor(lsum, 32, 64);                // full sum for row q = lr
    float linv = 1.f / lsum;
    float inv[4];
#pragma unroll
    for (int r = 0; r < 4; ++r)
        inv[r] = __shfl(linv, (lg << 4) + lg * 4 + r, 64); // for rows q=lg*4+r
    const int b = h >> 3, n = h & 7;
#pragma unroll
    for (int ni = 0; ni < 8; ++ni)
#pragma unroll
        for (int r = 0; r < 4; ++r) {
            int trow = q0 + w * 16 + lg * 4 + r;
            AOg[((size_t)(b * 2048 + trow)) * 1024 + n * 128 + ni * 16 + lr] =
                f2bf(accO[ni][r] * inv[r]);
        }
}

// ------------------------------------------- blade mixing epilogue (+ split-K add)
__global__ __launch_bounds__(256) void k_mix(const float* __restrict__ out0,
                                             const float* __restrict__ out1,
                                             const float* __restrict__ alpha,
                                             float* __restrict__ fin) {
    constexpr int SI[42] = {1,1,1,1,1,1, 2,2,2,2,2,2, 3,3,3,3,3,3, 4,4,4,4,4,4,
                            5,5,5,5,5,5, 6,6,6,6,6,6, 7,7,7,7,7,7};
    constexpr int SJ[42] = {2,3,4,5,6,7, 1,3,4,5,6,7, 1,2,4,5,6,7, 1,2,3,5,6,7,
                            1,2,3,4,6,7, 1,2,3,4,5,7, 1,2,3,4,5,6};
    constexpr int TG[42] = {4,5,2,3,7,6, 4,6,1,7,3,5, 5,6,7,1,2,4, 2,1,7,6,5,3,
                            3,7,1,6,4,2, 7,3,2,5,4,1, 6,5,4,3,2,1};
    constexpr float SG[42] = {+1,+1,+1,+1,+1,+1, -1,+1,-1,-1,+1,-1, -1,-1,+1,-1,-1,+1,
                              -1,+1,+1,-1,+1,-1, -1,-1,+1,+1,-1,+1, +1,-1,+1,-1,+1,-1,
                              +1,-1,+1,-1,+1,-1};
    int idx = blockIdx.x * 256 + threadIdx.x;        // B*T * D
    int d = idx & 127, bt = idx >> 7;
    size_t base = (size_t)bt * 1024 + d;
    float o[8], r[8];
#pragma unroll
    for (int hh = 0; hh < 8; ++hh) {
        o[hh] = out0[base + hh * 128] + out1[base + hh * 128];
        r[hh] = o[hh];
    }
#pragma unroll
    for (int p = 0; p < 42; ++p)
        r[TG[p]] += alpha[SI[p] * 8 + SJ[p]] * SG[p] * o[SI[p]] * o[SJ[p]];
#pragma unroll
    for (int hh = 0; hh < 8; ++hh) fin[base + hh * 128] = r[hh];
}

// ---------------------------------------------------------------------------
extern "C" void kernel_launch(void* const* d_in, const int* in_sizes, int n_in,
                              void* d_out, int out_size, void* d_ws, size_t ws_size,
                              hipStream_t stream) {
    (void)in_sizes; (void)n_in; (void)out_size; (void)ws_size;
    const float* mv    = (const float*)d_in[0];
    const float* Wqkv  = (const float*)d_in[1];
    const float* Wo    = (const float*)d_in[2];
    const float* alpha = (const float*)d_in[3];
    float* outp = (float*)d_out;
    char* ws = (char*)d_ws;

    // workspace layout (bytes); AO overlays Xbf; outF (32 MB contiguous, both
    // split-K halves) overlays QKV+Qr (dead after rope/vtrans and attn resp.)
    uint16_t* Xbf  = (uint16_t*)(ws + 0);            //  8 MB  [4096][1024]
    uint16_t* Wqt  = (uint16_t*)(ws + 8388608);      //  6 MB  [3072][1024]
    uint16_t* Wot  = (uint16_t*)(ws + 14680064);     //  2 MB  [1024][1024]
    uint16_t* QKV  = (uint16_t*)(ws + 16777216);     // 24 MB  [4096][3072]
    uint16_t* Qr   = (uint16_t*)(ws + 41943040);     //  8 MB  [16][2048][128]
    uint16_t* Kr   = (uint16_t*)(ws + 50331648);     //  8 MB
    uint16_t* Vt   = (uint16_t*)(ws + 58720256);     //  8 MB  [16][128][2048]
    float*    ctab = (float*)(ws + 67108864);        // 0.5 MB
    float*    stab = (float*)(ws + 67633152);        // 0.5 MB
    uint16_t* AO   = (uint16_t*)(ws + 0);            // overlay (X dead after GEMM1)
    float*    outF0 = (float*)(ws + 16777216);       // 16 MB half 0
    float*    outF1 = (float*)(ws + 33554432);       // 16 MB half 1 (= outF0 + 4M floats)

    k_cast  <<<4096, 256, 0, stream>>>(mv, Xbf, 4096 * 1024);
    k_wtrans<<<dim3(48, 16), 256, 0, stream>>>(Wqkv, Wqt, 1024, 3072);
    k_wtrans<<<dim3(16, 16), 256, 0, stream>>>(Wo, Wot, 1024, 1024);
    k_tab   <<<512, 256, 0, stream>>>(ctab, stab);
    k_gemm<uint16_t><<<dim3(24, 32), 256, 0, stream>>>(Xbf, Wqt, QKV, 4096, 3072, 1024);
    k_rope  <<<8192, 256, 0, stream>>>(QKV, ctab, stab, Qr, Kr);
    k_vtrans<<<dim3(2, 32, 16), 256, 0, stream>>>(QKV, Vt);
    k_attn  <<<512, 256, 0, stream>>>(Qr, Kr, Vt, AO);
    k_gemm2s<<<dim3(8, 32, 2), 256, 0, stream>>>(AO, Wot, outF0);  // z=1 -> outF1
    k_mix   <<<2048, 256, 0, stream>>>(outF0, outF1, alpha, outp);
}

// Round 10
// 137.042 us; speedup vs baseline: 2.1169x; 1.0681x over previous
//
#include <hip/hip_runtime.h>
#include <stdint.h>

// ---------------------------------------------------------------------------
// GeometricAttention: x@Wqkv (+fused RoPE/V-transpose epilogue) -> causal MHA
// -> @Wo (split-K) -> blade mixing.
// B=2 T=2048 N=8 D=128, d_model=1024. bf16 MFMA pipeline, fp32 accum.
// ---------------------------------------------------------------------------

typedef __attribute__((ext_vector_type(8)))  __bf16 bf16x8;
typedef __attribute__((ext_vector_type(4)))  float  f32x4;

__device__ __forceinline__ uint16_t f2bf(float f) {
    uint32_t u = __float_as_uint(f);
    u += 0x7FFFu + ((u >> 16) & 1u);           // RNE
    return (uint16_t)(u >> 16);
}
__device__ __forceinline__ float bf2f(uint16_t h) {
    return __uint_as_float(((uint32_t)h) << 16);
}

__device__ __forceinline__ void gload_lds16(const void* g, void* l) {
    __builtin_amdgcn_global_load_lds(
        (__attribute__((address_space(1))) void*)g,
        (__attribute__((address_space(3))) void*)l, 16, 0, 0);
}

// ---------------------------------------------------------------- cast fp32->bf16
__global__ __launch_bounds__(256) void k_cast(const float* __restrict__ in,
                                              uint16_t* __restrict__ out, int n) {
    int i = blockIdx.x * 256 + threadIdx.x;          // one float4 per thread
    if (i * 4 >= n) return;
    float4 v = ((const float4*)in)[i];
    ushort4 o = make_ushort4(f2bf(v.x), f2bf(v.y), f2bf(v.z), f2bf(v.w));
    ((ushort4*)out)[i] = o;
}

// ------------------------------------------------- transpose W [K][N] -> Wt [N][K] bf16
__global__ __launch_bounds__(256) void k_wtrans(const float* __restrict__ W,
                                                uint16_t* __restrict__ Wt,
                                                int K, int N) {
    __shared__ uint16_t tile[64][65];
    const int k0 = blockIdx.y * 64, n0 = blockIdx.x * 64;
    const int c = threadIdx.x & 63, r4 = threadIdx.x >> 6;
#pragma unroll
    for (int i = 0; i < 16; ++i) {
        int r = r4 + i * 4;
        tile[r][c] = f2bf(W[(size_t)(k0 + r) * N + n0 + c]);
    }
    __syncthreads();
#pragma unroll
    for (int i = 0; i < 16; ++i) {
        int r = r4 + i * 4;
        Wt[(size_t)(n0 + r) * K + k0 + c] = tile[c][r];
    }
}

// ---------------------------------------------------------------- RoPE tables
__global__ __launch_bounds__(256) void k_tab(float* __restrict__ ct,
                                             float* __restrict__ st) {
    int i = blockIdx.x * 256 + threadIdx.x;          // 2048*64
    int t = i >> 6, f = i & 63;
    float inv = expf(-(float)f * 0.14391156830441f); // ln(10000)/64
    float ang = (float)t * inv;
    ct[i] = cosf(ang);
    st[i] = sinf(ang);
}

// ---------------------- QKV GEMM with fused RoPE / V-transpose epilogue
// C-tile (128x128) of X @ Wqkv^T; n-tile bx: section = bx>>3 (0=Q,1=K,2=V),
// head = bx&7 — each tile is one head's full D=128, so rope pairs (d,d+64)
// are tile-local. acc -> LDS bf16 [128][132] (pad: column reads for V), one
// barrier, then write directly in the attention-ready layouts:
//   Q/K: rope applied, out [h][T][128]; V: transposed, out [h][128][T].
// Eliminates the 24MB QKV intermediate + k_rope + k_vtrans (72MB -> 24MB).
__global__ __launch_bounds__(256) void k_gemmqkv(const uint16_t* __restrict__ A,
                                                 const uint16_t* __restrict__ Bt,
                                                 const float* __restrict__ ct,
                                                 const float* __restrict__ st,
                                                 uint16_t* __restrict__ Qr,
                                                 uint16_t* __restrict__ Kr,
                                                 uint16_t* __restrict__ Vt) {
    __shared__ uint16_t Atile[128 * 32];
    __shared__ uint16_t Btile[128 * 32];
    __shared__ uint16_t Tl[128][132];                // +4 pad
    const int bx = blockIdx.x;                       // 0..23
    const int m0 = blockIdx.y << 7, n0 = bx << 7;
    const int sec = bx >> 3, head = bx & 7;
    const int tid = threadIdx.x;
    const int l = tid & 63, w = tid >> 6;
    const int lr = l & 15, lg = l >> 4;
    const int wm = (w >> 1) << 6, wn = (w & 1) << 6;
    const int K = 1024;

    f32x4 acc[4][4];
#pragma unroll
    for (int i = 0; i < 4; ++i)
#pragma unroll
        for (int j = 0; j < 4; ++j) acc[i][j] = (f32x4){0.f, 0.f, 0.f, 0.f};

    for (int kt = 0; kt < 32; ++kt) {
        const int k0 = kt << 5;
        __syncthreads();
#pragma unroll
        for (int c = 0; c < 4; ++c) {
            int idx = c * 256 + tid;                 // 0..1023, wave-contiguous
            if (idx < 512) {
                int r = idx >> 2, kc = (idx & 3) << 3;
                gload_lds16(A + (size_t)(m0 + r) * K + k0 + kc, &Atile[idx * 8]);
            } else {
                int i2 = idx - 512;
                int r = i2 >> 2, kc = (i2 & 3) << 3;
                gload_lds16(Bt + (size_t)(n0 + r) * K + k0 + kc, &Btile[i2 * 8]);
            }
        }
        __syncthreads();
        bf16x8 af[4], bfv[4];
#pragma unroll
        for (int i = 0; i < 4; ++i) {
            af[i]  = *(const bf16x8*)(&Atile[(wm + i * 16 + lr) * 32 + lg * 8]);
            bfv[i] = *(const bf16x8*)(&Btile[(wn + i * 16 + lr) * 32 + lg * 8]);
        }
#pragma unroll
        for (int mi = 0; mi < 4; ++mi)
#pragma unroll
            for (int ni = 0; ni < 4; ++ni)
                acc[mi][ni] = __builtin_amdgcn_mfma_f32_16x16x32_bf16(
                    af[mi], bfv[ni], acc[mi][ni], 0, 0, 0);
    }

    // ---- epilogue: acc -> LDS bf16 tile (C layout: col=lane&15, row=lg*4+r)
    __syncthreads();                                 // Atile/Btile reads done
#pragma unroll
    for (int mi = 0; mi < 4; ++mi)
#pragma unroll
        for (int ni = 0; ni < 4; ++ni)
#pragma unroll
            for (int r = 0; r < 4; ++r)
                Tl[wm + mi * 16 + lg * 4 + r][wn + ni * 16 + lr] =
                    f2bf(acc[mi][ni][r]);
    __syncthreads();

    const int b = m0 >> 11, t0 = m0 & 2047;
    const size_t hidx = (size_t)(b * 8 + head);
    if (sec < 2) {                                   // Q or K: rope + write
        uint16_t* outp = (sec == 0 ? Qr : Kr) + (hidx * 2048 + t0) * 128;
#pragma unroll
        for (int it = 0; it < 8; ++it) {
            int lin = it * 256 + tid;
            int tr = lin >> 4, d0 = (lin & 15) * 4;
            ushort4 lo = *(const ushort4*)&Tl[tr][d0];
            ushort4 hi = *(const ushort4*)&Tl[tr][d0 + 64];
            float4 cv = *(const float4*)&ct[(size_t)(t0 + tr) * 64 + d0];
            float4 sv = *(const float4*)&st[(size_t)(t0 + tr) * 64 + d0];
            ushort4 o1, o2;
            o1.x = f2bf(bf2f(lo.x) * cv.x - bf2f(hi.x) * sv.x);
            o2.x = f2bf(bf2f(hi.x) * cv.x + bf2f(lo.x) * sv.x);
            o1.y = f2bf(bf2f(lo.y) * cv.y - bf2f(hi.y) * sv.y);
            o2.y = f2bf(bf2f(hi.y) * cv.y + bf2f(lo.y) * sv.y);
            o1.z = f2bf(bf2f(lo.z) * cv.z - bf2f(hi.z) * sv.z);
            o2.z = f2bf(bf2f(hi.z) * cv.z + bf2f(lo.z) * sv.z);
            o1.w = f2bf(bf2f(lo.w) * cv.w - bf2f(hi.w) * sv.w);
            o2.w = f2bf(bf2f(hi.w) * cv.w + bf2f(lo.w) * sv.w);
            *(ushort4*)&outp[(size_t)tr * 128 + d0]      = o1;
            *(ushort4*)&outp[(size_t)tr * 128 + d0 + 64] = o2;
        }
    } else {                                         // V: transpose to [h][D][T]
        uint16_t* vp = Vt + hidx * 128 * 2048;
#pragma unroll
        for (int it = 0; it < 8; ++it) {
            int lin = it * 256 + tid;
            int d = lin >> 4, tq = (lin & 15) * 8;
            ushort4 v0 = make_ushort4(Tl[tq + 0][d], Tl[tq + 1][d],
                                      Tl[tq + 2][d], Tl[tq + 3][d]);
            ushort4 v1 = make_ushort4(Tl[tq + 4][d], Tl[tq + 5][d],
                                      Tl[tq + 6][d], Tl[tq + 7][d]);
            *(ushort4*)&vp[(size_t)d * 2048 + t0 + tq]     = v0;
            *(ushort4*)&vp[(size_t)d * 2048 + t0 + tq + 4] = v1;
        }
    }
}

// -------------------------------------- split-K out-proj GEMM (occupancy fix)
// M=4096, N=1024 -> 128^2 tiles give only 256 blocks = 1 block/CU (m102-style
// starvation). Single launch, grid (8,32,2): z = K-half. 512 blocks = 2/CU.
// Halves write C and C + 4M floats (contiguous 32 MB); summed in k_mix.
__global__ __launch_bounds__(256) void k_gemm2s(const uint16_t* __restrict__ A,
                                                const uint16_t* __restrict__ Bt,
                                                float* __restrict__ C) {
    __shared__ uint16_t Atile[128 * 32];
    __shared__ uint16_t Btile[128 * 32];
    const int kz = blockIdx.z;
    A  += (size_t)kz * 512;                          // k-offset within row
    Bt += (size_t)kz * 512;
    C  += (size_t)kz * (4096u * 1024u);              // partial-output buffer
    const int m0 = blockIdx.y << 7, n0 = blockIdx.x << 7;
    const int tid = threadIdx.x;
    const int l = tid & 63, w = tid >> 6;
    const int lr = l & 15, lg = l >> 4;
    const int wm = (w >> 1) << 6, wn = (w & 1) << 6;

    f32x4 acc[4][4];
#pragma unroll
    for (int i = 0; i < 4; ++i)
#pragma unroll
        for (int j = 0; j < 4; ++j) acc[i][j] = (f32x4){0.f, 0.f, 0.f, 0.f};

    for (int kt = 0; kt < 16; ++kt) {                // K_half = 512 = 16 x 32
        const int k0 = kt << 5;
        __syncthreads();
#pragma unroll
        for (int c = 0; c < 4; ++c) {
            int idx = c * 256 + tid;
            if (idx < 512) {
                int r = idx >> 2, kc = (idx & 3) << 3;
                gload_lds16(A + (size_t)(m0 + r) * 1024 + k0 + kc, &Atile[idx * 8]);
            } else {
                int i2 = idx - 512;
                int r = i2 >> 2, kc = (i2 & 3) << 3;
                gload_lds16(Bt + (size_t)(n0 + r) * 1024 + k0 + kc, &Btile[i2 * 8]);
            }
        }
        __syncthreads();
        bf16x8 af[4], bfv[4];
#pragma unroll
        for (int i = 0; i < 4; ++i) {
            af[i]  = *(const bf16x8*)(&Atile[(wm + i * 16 + lr) * 32 + lg * 8]);
            bfv[i] = *(const bf16x8*)(&Btile[(wn + i * 16 + lr) * 32 + lg * 8]);
        }
#pragma unroll
        for (int mi = 0; mi < 4; ++mi)
#pragma unroll
            for (int ni = 0; ni < 4; ++ni)
                acc[mi][ni] = __builtin_amdgcn_mfma_f32_16x16x32_bf16(
                    af[mi], bfv[ni], acc[mi][ni], 0, 0, 0);
    }
#pragma unroll
    for (int mi = 0; mi < 4; ++mi)
#pragma unroll
        for (int ni = 0; ni < 4; ++ni)
#pragma unroll
            for (int r = 0; r < 4; ++r) {
                int row = m0 + wm + mi * 16 + lg * 4 + r;
                int col = n0 + wn + ni * 16 + lr;
                C[(size_t)row * 1024 + col] = acc[mi][ni][r];
            }
}

// --------------------------------------------------- causal flash attention
// R3-proven kernel (58 us): swapped QK^T (S^T = mfma(K,Q)) so each lane holds
// P[q=lr][16 k] lane-locally; softmax state scalar/lane, common path has NO
// cross-lane ops. P -> LDS as packed b64 (cvt_pk_bf16 pairs), read back as
// swizzled b128 A-frags. K/V double-buffered via global_load_lds (linear
// dest, inverse-swizzled src). Heavy/light block pairing.
__global__ __launch_bounds__(256) void k_attn(const uint16_t* __restrict__ Qg,
                                              const uint16_t* __restrict__ Kg,
                                              const uint16_t* __restrict__ Vtg,
                                              uint16_t* __restrict__ AOg) {
    __shared__ uint16_t Klds[2][64 * 128];           // 16 KB each, XOR-swizzled
    __shared__ uint16_t Vlds[2][128 * 64];           // 16 KB each, XOR-swizzled
    __shared__ uint16_t Plds[4][16 * 64];            // 2 KB per wave, swizzled

    const int bx = blockIdx.x;
    const int h  = bx & 15;
    const int t4 = (bx >> 4) & 15;
    const int qt = (bx < 256) ? (31 - t4) : t4;      // heavy/light pairing
    const int q0 = qt * 64;
    const int tid = threadIdx.x;
    const int l = tid & 63, w = tid >> 6;
    const int lr = l & 15, lg = l >> 4;
    const size_t headTD = (size_t)h * (2048 * 128);
    const uint16_t* Kh = Kg + headTD;
    const uint16_t* Vh = Vtg + headTD;

    bf16x8 qf[4];
    {
        const uint16_t* qp = Qg + headTD + (size_t)(q0 + w * 16 + lr) * 128 + lg * 8;
#pragma unroll
        for (int kc = 0; kc < 4; ++kc) qf[kc] = *(const bf16x8*)(qp + kc * 32);
    }

    f32x4 accO[8];
#pragma unroll
    for (int i = 0; i < 8; ++i) accO[i] = (f32x4){0.f, 0.f, 0.f, 0.f};
    float mrun = -1e30f, lrun = 0.f;                 // per-lane row q = lr

    const float SL2E = 0.08838834764831845f * 1.4426950408889634f; // scale*log2e
    const int   swz  = (lr & 7) << 4;                // per-lane swizzle (row=lr)
    uint16_t* Pw = &Plds[w][0];

    auto STAGE = [&](int buf, int k0) {
#pragma unroll
        for (int p = 0; p < 4; ++p) {                // K: 64x128 rows of 256B
            int u = p * 256 + tid;                   // 16B chunk id
            int row = u >> 4;
            int c16 = (u & 15) ^ (row & 7);          // inverse swizzle on SOURCE
            gload_lds16(Kh + (size_t)(k0 + row) * 128 + c16 * 8,
                        (char*)&Klds[buf][0] + u * 16);
        }
#pragma unroll
        for (int p = 0; p < 4; ++p) {                // V: 128x64 rows of 128B
            int u = p * 256 + tid;
            int d = u >> 3;
            int c8 = (u & 7) ^ (d & 7);
            gload_lds16(Vh + (size_t)d * 2048 + k0 + c8 * 8,
                        (char*)&Vlds[buf][0] + u * 16);
        }
    };

    STAGE(0, 0);                                     // prologue

    for (int kt = 0; kt <= qt; ++kt) {
        asm volatile("s_waitcnt vmcnt(0)" ::: "memory"); // tile kt's loads done
        __builtin_amdgcn_s_barrier();
        __builtin_amdgcn_sched_barrier(0);
        if (kt < qt) STAGE((kt + 1) & 1, (kt + 1) * 64); // async prefetch

        const char* Kb = (const char*)&Klds[kt & 1][0];
        const char* Vb = (const char*)&Vlds[kt & 1][0];

        // ---- S^T = K Q^T : lane holds S[q=lr][k = cg*16 + lg*4 + r] ------
        float sv[4][4];
        __builtin_amdgcn_s_setprio(1);
#pragma unroll
        for (int cg = 0; cg < 4; ++cg) {
            f32x4 a = (f32x4){0.f, 0.f, 0.f, 0.f};
#pragma unroll
            for (int kc = 0; kc < 4; ++kc) {
                int kb = (cg * 16 + lr) * 256 + ((kc * 64 + lg * 16) ^ swz);
                bf16x8 kf = *(const bf16x8*)(Kb + kb);
                a = __builtin_amdgcn_mfma_f32_16x16x32_bf16(kf, qf[kc], a, 0, 0, 0);
            }
#pragma unroll
            for (int r = 0; r < 4; ++r) sv[cg][r] = a[r];
        }
        __builtin_amdgcn_s_setprio(0);

        if (kt == qt) {                              // causal mask, diagonal tile
#pragma unroll
            for (int cg = 0; cg < 4; ++cg)
#pragma unroll
                for (int r = 0; r < 4; ++r)
                    if (cg * 16 + lg * 4 + r > w * 16 + lr) sv[cg][r] = -1e30f;
        }

        // ---- defer-max online softmax (lane-local row) -------------------
        float pml = sv[0][0];
#pragma unroll
        for (int cg = 0; cg < 4; ++cg)
#pragma unroll
            for (int r = 0; r < 4; ++r) pml = fmaxf(pml, sv[cg][r]);

        if (!__all(pml * SL2E <= mrun + 11.f)) {     // rare: true max + rescale
            float mx = pml;
            mx = fmaxf(mx, __shfl_xor(mx, 16, 64));
            mx = fmaxf(mx, __shfl_xor(mx, 32, 64));  // full row max (q = lr)
            float mn = fmaxf(mrun, mx * SL2E);
            float corr = exp2f(mrun - mn);
            mrun = mn;
            lrun *= corr;                            // lane-partial sum scales too
            float ca[4];
#pragma unroll
            for (int r = 0; r < 4; ++r)              // corr for accO rows q=lg*4+r
                ca[r] = __shfl(corr, (lg << 4) + lg * 4 + r, 64);
#pragma unroll
            for (int i = 0; i < 8; ++i)
#pragma unroll
                for (int r = 0; r < 4; ++r) accO[i][r] *= ca[r];
        }

        float psum = 0.f;
        float p[4][4];
#pragma unroll
        for (int cg = 0; cg < 4; ++cg)
#pragma unroll
            for (int r = 0; r < 4; ++r) {
                p[cg][r] = exp2f(fmaf(sv[cg][r], SL2E, -mrun));
                psum += p[cg][r];
            }
        lrun += psum;

        // pack P pairs -> b64 LDS writes (row q=lr, k = 16cg+4lg .. +3)
#pragma unroll
        for (int cg = 0; cg < 4; ++cg) {
            uint32_t w0, w1;
            asm("v_cvt_pk_bf16_f32 %0, %1, %2" : "=v"(w0) : "v"(p[cg][0]), "v"(p[cg][1]));
            asm("v_cvt_pk_bf16_f32 %0, %1, %2" : "=v"(w1) : "v"(p[cg][2]), "v"(p[cg][3]));
            uint2 pr; pr.x = w0; pr.y = w1;
            *(uint2*)((char*)Pw + lr * 128 + ((cg * 32 + lg * 8) ^ swz)) = pr;
        }

        asm volatile("" ::: "memory");               // order P stores before reads
        bf16x8 pf[2];
#pragma unroll
        for (int c = 0; c < 2; ++c)
            pf[c] = *(const bf16x8*)((char*)Pw + lr * 128 + ((c * 64 + lg * 16) ^ swz));

        __builtin_amdgcn_s_setprio(1);
#pragma unroll
        for (int ni = 0; ni < 8; ++ni)
#pragma unroll
            for (int c = 0; c < 2; ++c) {
                int vb = (ni * 16 + lr) * 128 + ((c * 64 + lg * 16) ^ swz);
                bf16x8 vf = *(const bf16x8*)(Vb + vb);
                accO[ni] = __builtin_amdgcn_mfma_f32_16x16x32_bf16(pf[c], vf, accO[ni], 0, 0, 0);
            }
        __builtin_amdgcn_s_setprio(0);
    }

    // row sums: reduce lane-partials across the 4 lg lanes, then redistribute
    float lsum = lrun;
    lsum += __shfl_xor(lsum, 16, 64);
    lsum += __shfl_xor(lsum, 32, 64);                // full sum for row q = lr
    float linv = 1.f / lsum;
    float inv[4];
#pragma unroll
    for (int r = 0; r < 4; ++r)
        inv[r] = __shfl(linv, (lg << 4) + lg * 4 + r, 64); // for rows q=lg*4+r
    const int b = h >> 3, n = h & 7;
#pragma unroll
    for (int ni = 0; ni < 8; ++ni)
#pragma unroll
        for (int r = 0; r < 4; ++r) {
            int trow = q0 + w * 16 + lg * 4 + r;
            AOg[((size_t)(b * 2048 + trow)) * 1024 + n * 128 + ni * 16 + lr] =
                f2bf(accO[ni][r] * inv[r]);
        }
}

// ------------------------------------------- blade mixing epilogue (+ split-K add)
__global__ __launch_bounds__(256) void k_mix(const float* __restrict__ out0,
                                             const float* __restrict__ out1,
                                             const float* __restrict__ alpha,
                                             float* __restrict__ fin) {
    constexpr int SI[42] = {1,1,1,1,1,1, 2,2,2,2,2,2, 3,3,3,3,3,3, 4,4,4,4,4,4,
                            5,5,5,5,5,5, 6,6,6,6,6,6, 7,7,7,7,7,7};
    constexpr int SJ[42] = {2,3,4,5,6,7, 1,3,4,5,6,7, 1,2,4,5,6,7, 1,2,3,5,6,7,
                            1,2,3,4,6,7, 1,2,3,4,5,7, 1,2,3,4,5,6};
    constexpr int TG[42] = {4,5,2,3,7,6, 4,6,1,7,3,5, 5,6,7,1,2,4, 2,1,7,6,5,3,
                            3,7,1,6,4,2, 7,3,2,5,4,1, 6,5,4,3,2,1};
    constexpr float SG[42] = {+1,+1,+1,+1,+1,+1, -1,+1,-1,-1,+1,-1, -1,-1,+1,-1,-1,+1,
                              -1,+1,+1,-1,+1,-1, -1,-1,+1,+1,-1,+1, +1,-1,+1,-1,+1,-1,
                              +1,-1,+1,-1,+1,-1};
    int idx = blockIdx.x * 256 + threadIdx.x;        // B*T * D
    int d = idx & 127, bt = idx >> 7;
    size_t base = (size_t)bt * 1024 + d;
    float o[8], r[8];
#pragma unroll
    for (int hh = 0; hh < 8; ++hh) {
        o[hh] = out0[base + hh * 128] + out1[base + hh * 128];
        r[hh] = o[hh];
    }
#pragma unroll
    for (int p = 0; p < 42; ++p)
        r[TG[p]] += alpha[SI[p] * 8 + SJ[p]] * SG[p] * o[SI[p]] * o[SJ[p]];
#pragma unroll
    for (int hh = 0; hh < 8; ++hh) fin[base + hh * 128] = r[hh];
}

// ---------------------------------------------------------------------------
extern "C" void kernel_launch(void* const* d_in, const int* in_sizes, int n_in,
                              void* d_out, int out_size, void* d_ws, size_t ws_size,
                              hipStream_t stream) {
    (void)in_sizes; (void)n_in; (void)out_size; (void)ws_size;
    const float* mv    = (const float*)d_in[0];
    const float* Wqkv  = (const float*)d_in[1];
    const float* Wo    = (const float*)d_in[2];
    const float* alpha = (const float*)d_in[3];
    float* outp = (float*)d_out;
    char* ws = (char*)d_ws;

    // workspace layout (bytes); AO overlays Xbf; outF0/outF1 live in the
    // region formerly used by QKV (now never written) + Qr (dead after attn).
    uint16_t* Xbf  = (uint16_t*)(ws + 0);            //  8 MB  [4096][1024]
    uint16_t* Wqt  = (uint16_t*)(ws + 8388608);      //  6 MB  [3072][1024]
    uint16_t* Wot  = (uint16_t*)(ws + 14680064);     //  2 MB  [1024][1024]
    uint16_t* Qr   = (uint16_t*)(ws + 41943040);     //  8 MB  [16][2048][128]
    uint16_t* Kr   = (uint16_t*)(ws + 50331648);     //  8 MB
    uint16_t* Vt   = (uint16_t*)(ws + 58720256);     //  8 MB  [16][128][2048]
    float*    ctab = (float*)(ws + 67108864);        // 0.5 MB
    float*    stab = (float*)(ws + 67633152);        // 0.5 MB
    uint16_t* AO   = (uint16_t*)(ws + 0);            // overlay (X dead after GEMM1)
    float*    outF0 = (float*)(ws + 16777216);       // 16 MB half 0
    float*    outF1 = (float*)(ws + 33554432);       // 16 MB half 1 (= outF0 + 4M floats)

    k_cast   <<<4096, 256, 0, stream>>>(mv, Xbf, 4096 * 1024);
    k_wtrans <<<dim3(48, 16), 256, 0, stream>>>(Wqkv, Wqt, 1024, 3072);
    k_wtrans <<<dim3(16, 16), 256, 0, stream>>>(Wo, Wot, 1024, 1024);
    k_tab    <<<512, 256, 0, stream>>>(ctab, stab);
    k_gemmqkv<<<dim3(24, 32), 256, 0, stream>>>(Xbf, Wqt, ctab, stab, Qr, Kr, Vt);
    k_attn   <<<512, 256, 0, stream>>>(Qr, Kr, Vt, AO);
    k_gemm2s <<<dim3(8, 32, 2), 256, 0, stream>>>(AO, Wot, outF0);  // z=1 -> outF1
    k_mix    <<<2048, 256, 0, stream>>>(outF0, outF1, alpha, outp);
}

// Round 11
// 133.893 us; speedup vs baseline: 2.1667x; 1.0235x over previous
//
#include <hip/hip_runtime.h>
#include <stdint.h>

// ---------------------------------------------------------------------------
// GeometricAttention: x@Wqkv (+fused RoPE/V-transpose epilogue) -> causal MHA
// -> @Wo (split-K, 128x64 tiles) -> blade mixing (float4).
// B=2 T=2048 N=8 D=128, d_model=1024. bf16 MFMA pipeline, fp32 accum.
// ---------------------------------------------------------------------------

typedef __attribute__((ext_vector_type(8)))  __bf16 bf16x8;
typedef __attribute__((ext_vector_type(4)))  float  f32x4;

__device__ __forceinline__ uint16_t f2bf(float f) {
    uint32_t u = __float_as_uint(f);
    u += 0x7FFFu + ((u >> 16) & 1u);           // RNE
    return (uint16_t)(u >> 16);
}
__device__ __forceinline__ float bf2f(uint16_t h) {
    return __uint_as_float(((uint32_t)h) << 16);
}

__device__ __forceinline__ void gload_lds16(const void* g, void* l) {
    __builtin_amdgcn_global_load_lds(
        (__attribute__((address_space(1))) void*)g,
        (__attribute__((address_space(3))) void*)l, 16, 0, 0);
}

// ---------------------------------------------------------------- cast fp32->bf16
__global__ __launch_bounds__(256) void k_cast(const float* __restrict__ in,
                                              uint16_t* __restrict__ out, int n) {
    int i = blockIdx.x * 256 + threadIdx.x;          // one float4 per thread
    if (i * 4 >= n) return;
    float4 v = ((const float4*)in)[i];
    ushort4 o = make_ushort4(f2bf(v.x), f2bf(v.y), f2bf(v.z), f2bf(v.w));
    ((ushort4*)out)[i] = o;
}

// ------------------------------------------------- transpose W [K][N] -> Wt [N][K] bf16
__global__ __launch_bounds__(256) void k_wtrans(const float* __restrict__ W,
                                                uint16_t* __restrict__ Wt,
                                                int K, int N) {
    __shared__ uint16_t tile[64][65];
    const int k0 = blockIdx.y * 64, n0 = blockIdx.x * 64;
    const int c = threadIdx.x & 63, r4 = threadIdx.x >> 6;
#pragma unroll
    for (int i = 0; i < 16; ++i) {
        int r = r4 + i * 4;
        tile[r][c] = f2bf(W[(size_t)(k0 + r) * N + n0 + c]);
    }
    __syncthreads();
#pragma unroll
    for (int i = 0; i < 16; ++i) {
        int r = r4 + i * 4;
        Wt[(size_t)(n0 + r) * K + k0 + c] = tile[c][r];
    }
}

// ---------------------------------------------------------------- RoPE tables
__global__ __launch_bounds__(256) void k_tab(float* __restrict__ ct,
                                             float* __restrict__ st) {
    int i = blockIdx.x * 256 + threadIdx.x;          // 2048*64
    int t = i >> 6, f = i & 63;
    float inv = expf(-(float)f * 0.14391156830441f); // ln(10000)/64
    float ang = (float)t * inv;
    ct[i] = cosf(ang);
    st[i] = sinf(ang);
}

// ---------------------- QKV GEMM with fused RoPE / V-transpose epilogue
// XCD-aware swizzle (T1): lin = y*24+x (hw dispatch order), logical =
// (lin%8)*96 + lin/8 -> each XCD gets 4 consecutive m-tiles (1MB of A
// L2-resident) while streaming B. 768 blocks, 768%8==0 -> bijective.
// n-tile: section = n>>3 (0=Q,1=K,2=V), head = n&7; rope pairs (d,d+64)
// are tile-local. acc -> LDS bf16 [128][132], then write attention-ready:
// Q/K roped [h][T][128]; V transposed [h][128][T].
__global__ __launch_bounds__(256) void k_gemmqkv(const uint16_t* __restrict__ A,
                                                 const uint16_t* __restrict__ Bt,
                                                 const float* __restrict__ ct,
                                                 const float* __restrict__ st,
                                                 uint16_t* __restrict__ Qr,
                                                 uint16_t* __restrict__ Kr,
                                                 uint16_t* __restrict__ Vt) {
    __shared__ uint16_t Atile[128 * 32];
    __shared__ uint16_t Btile[128 * 32];
    __shared__ uint16_t Tl[128][132];                // +4 pad
    const int lin = blockIdx.y * 24 + blockIdx.x;
    const int logical = (lin & 7) * 96 + (lin >> 3); // XCD swizzle (bijective)
    const int bx = logical % 24;                     // n-tile 0..23
    const int m0 = (logical / 24) << 7, n0 = bx << 7;
    const int sec = bx >> 3, head = bx & 7;
    const int tid = threadIdx.x;
    const int l = tid & 63, w = tid >> 6;
    const int lr = l & 15, lg = l >> 4;
    const int wm = (w >> 1) << 6, wn = (w & 1) << 6;
    const int K = 1024;

    f32x4 acc[4][4];
#pragma unroll
    for (int i = 0; i < 4; ++i)
#pragma unroll
        for (int j = 0; j < 4; ++j) acc[i][j] = (f32x4){0.f, 0.f, 0.f, 0.f};

    for (int kt = 0; kt < 32; ++kt) {
        const int k0 = kt << 5;
        __syncthreads();
#pragma unroll
        for (int c = 0; c < 4; ++c) {
            int idx = c * 256 + tid;                 // 0..1023, wave-contiguous
            if (idx < 512) {
                int r = idx >> 2, kc = (idx & 3) << 3;
                gload_lds16(A + (size_t)(m0 + r) * K + k0 + kc, &Atile[idx * 8]);
            } else {
                int i2 = idx - 512;
                int r = i2 >> 2, kc = (i2 & 3) << 3;
                gload_lds16(Bt + (size_t)(n0 + r) * K + k0 + kc, &Btile[i2 * 8]);
            }
        }
        __syncthreads();
        bf16x8 af[4], bfv[4];
#pragma unroll
        for (int i = 0; i < 4; ++i) {
            af[i]  = *(const bf16x8*)(&Atile[(wm + i * 16 + lr) * 32 + lg * 8]);
            bfv[i] = *(const bf16x8*)(&Btile[(wn + i * 16 + lr) * 32 + lg * 8]);
        }
#pragma unroll
        for (int mi = 0; mi < 4; ++mi)
#pragma unroll
            for (int ni = 0; ni < 4; ++ni)
                acc[mi][ni] = __builtin_amdgcn_mfma_f32_16x16x32_bf16(
                    af[mi], bfv[ni], acc[mi][ni], 0, 0, 0);
    }

    // ---- epilogue: acc -> LDS bf16 tile (C layout: col=lane&15, row=lg*4+r)
    __syncthreads();                                 // Atile/Btile reads done
#pragma unroll
    for (int mi = 0; mi < 4; ++mi)
#pragma unroll
        for (int ni = 0; ni < 4; ++ni)
#pragma unroll
            for (int r = 0; r < 4; ++r)
                Tl[wm + mi * 16 + lg * 4 + r][wn + ni * 16 + lr] =
                    f2bf(acc[mi][ni][r]);
    __syncthreads();

    const int b = m0 >> 11, t0 = m0 & 2047;
    const size_t hidx = (size_t)(b * 8 + head);
    if (sec < 2) {                                   // Q or K: rope + write
        uint16_t* outp = (sec == 0 ? Qr : Kr) + (hidx * 2048 + t0) * 128;
#pragma unroll
        for (int it = 0; it < 8; ++it) {
            int lin2 = it * 256 + tid;
            int tr = lin2 >> 4, d0 = (lin2 & 15) * 4;
            ushort4 lo = *(const ushort4*)&Tl[tr][d0];
            ushort4 hi = *(const ushort4*)&Tl[tr][d0 + 64];
            float4 cv = *(const float4*)&ct[(size_t)(t0 + tr) * 64 + d0];
            float4 sv = *(const float4*)&st[(size_t)(t0 + tr) * 64 + d0];
            ushort4 o1, o2;
            o1.x = f2bf(bf2f(lo.x) * cv.x - bf2f(hi.x) * sv.x);
            o2.x = f2bf(bf2f(hi.x) * cv.x + bf2f(lo.x) * sv.x);
            o1.y = f2bf(bf2f(lo.y) * cv.y - bf2f(hi.y) * sv.y);
            o2.y = f2bf(bf2f(hi.y) * cv.y + bf2f(lo.y) * sv.y);
            o1.z = f2bf(bf2f(lo.z) * cv.z - bf2f(hi.z) * sv.z);
            o2.z = f2bf(bf2f(hi.z) * cv.z + bf2f(lo.z) * sv.z);
            o1.w = f2bf(bf2f(lo.w) * cv.w - bf2f(hi.w) * sv.w);
            o2.w = f2bf(bf2f(hi.w) * cv.w + bf2f(lo.w) * sv.w);
            *(ushort4*)&outp[(size_t)tr * 128 + d0]      = o1;
            *(ushort4*)&outp[(size_t)tr * 128 + d0 + 64] = o2;
        }
    } else {                                         // V: transpose to [h][D][T]
        uint16_t* vp = Vt + hidx * 128 * 2048;
#pragma unroll
        for (int it = 0; it < 8; ++it) {
            int lin2 = it * 256 + tid;
            int d = lin2 >> 4, tq = (lin2 & 15) * 8;
            ushort4 v0 = make_ushort4(Tl[tq + 0][d], Tl[tq + 1][d],
                                      Tl[tq + 2][d], Tl[tq + 3][d]);
            ushort4 v1 = make_ushort4(Tl[tq + 4][d], Tl[tq + 5][d],
                                      Tl[tq + 6][d], Tl[tq + 7][d]);
            *(ushort4*)&vp[(size_t)d * 2048 + t0 + tq]     = v0;
            *(ushort4*)&vp[(size_t)d * 2048 + t0 + tq + 4] = v1;
        }
    }
}

// -------------------------------------- split-K out-proj GEMM, 128x64 tiles
// M=4096, N=1024, K split in 2. Tile 128x64 -> grid (16,32,2) = 1024 blocks
// = 4 blocks/CU (12 KB LDS) vs 2/CU at 128^2 — doubles resident waves to
// hide the staging latency. Per-z XCD swizzle (512%8==0, bijective).
// Halves write C and C + 4M floats; summed in k_mix.
__global__ __launch_bounds__(256) void k_gemm2s(const uint16_t* __restrict__ A,
                                                const uint16_t* __restrict__ Bt,
                                                float* __restrict__ C) {
    __shared__ uint16_t Atile[128 * 32];             // 8 KB
    __shared__ uint16_t Btile[64 * 32];              // 4 KB
    const int kz = blockIdx.z;
    A  += (size_t)kz * 512;                          // k-offset within row
    Bt += (size_t)kz * 512;
    C  += (size_t)kz * (4096u * 1024u);              // partial-output buffer
    const int lin = blockIdx.y * 16 + blockIdx.x;
    const int logical = (lin & 7) * 64 + (lin >> 3); // XCD swizzle per z
    const int m0 = (logical >> 4) << 7, n0 = (logical & 15) << 6;
    const int tid = threadIdx.x;
    const int l = tid & 63, w = tid >> 6;
    const int lr = l & 15, lg = l >> 4;
    const int wm = (w >> 1) << 6, wn = (w & 1) << 5;

    f32x4 acc[4][2];
#pragma unroll
    for (int i = 0; i < 4; ++i)
#pragma unroll
        for (int j = 0; j < 2; ++j) acc[i][j] = (f32x4){0.f, 0.f, 0.f, 0.f};

    for (int kt = 0; kt < 16; ++kt) {                // K_half = 512 = 16 x 32
        const int k0 = kt << 5;
        __syncthreads();
#pragma unroll
        for (int c = 0; c < 3; ++c) {                // 768 chunks of 16B
            int idx = c * 256 + tid;
            if (idx < 512) {
                int r = idx >> 2, kc = (idx & 3) << 3;
                gload_lds16(A + (size_t)(m0 + r) * 1024 + k0 + kc, &Atile[idx * 8]);
            } else {
                int i2 = idx - 512;                  // 0..255: B 64 rows x 4
                int r = i2 >> 2, kc = (i2 & 3) << 3;
                gload_lds16(Bt + (size_t)(n0 + r) * 1024 + k0 + kc, &Btile[i2 * 8]);
            }
        }
        __syncthreads();
        bf16x8 af[4], bfv[2];
#pragma unroll
        for (int i = 0; i < 4; ++i)
            af[i] = *(const bf16x8*)(&Atile[(wm + i * 16 + lr) * 32 + lg * 8]);
#pragma unroll
        for (int j = 0; j < 2; ++j)
            bfv[j] = *(const bf16x8*)(&Btile[(wn + j * 16 + lr) * 32 + lg * 8]);
#pragma unroll
        for (int mi = 0; mi < 4; ++mi)
#pragma unroll
            for (int ni = 0; ni < 2; ++ni)
                acc[mi][ni] = __builtin_amdgcn_mfma_f32_16x16x32_bf16(
                    af[mi], bfv[ni], acc[mi][ni], 0, 0, 0);
    }
#pragma unroll
    for (int mi = 0; mi < 4; ++mi)
#pragma unroll
        for (int ni = 0; ni < 2; ++ni)
#pragma unroll
            for (int r = 0; r < 4; ++r) {
                int row = m0 + wm + mi * 16 + lg * 4 + r;
                int col = n0 + wn + ni * 16 + lr;
                C[(size_t)row * 1024 + col] = acc[mi][ni][r];
            }
}

// --------------------------------------------------- causal flash attention
// R3-proven kernel (58 us): swapped QK^T (S^T = mfma(K,Q)) so each lane holds
// P[q=lr][16 k] lane-locally; softmax state scalar/lane, common path has NO
// cross-lane ops. P -> LDS as packed b64 (cvt_pk_bf16 pairs), read back as
// swizzled b128 A-frags. K/V double-buffered via global_load_lds (linear
// dest, inverse-swizzled src). Heavy/light block pairing.
__global__ __launch_bounds__(256) void k_attn(const uint16_t* __restrict__ Qg,
                                              const uint16_t* __restrict__ Kg,
                                              const uint16_t* __restrict__ Vtg,
                                              uint16_t* __restrict__ AOg) {
    __shared__ uint16_t Klds[2][64 * 128];           // 16 KB each, XOR-swizzled
    __shared__ uint16_t Vlds[2][128 * 64];           // 16 KB each, XOR-swizzled
    __shared__ uint16_t Plds[4][16 * 64];            // 2 KB per wave, swizzled

    const int bx = blockIdx.x;
    const int h  = bx & 15;
    const int t4 = (bx >> 4) & 15;
    const int qt = (bx < 256) ? (31 - t4) : t4;      // heavy/light pairing
    const int q0 = qt * 64;
    const int tid = threadIdx.x;
    const int l = tid & 63, w = tid >> 6;
    const int lr = l & 15, lg = l >> 4;
    const size_t headTD = (size_t)h * (2048 * 128);
    const uint16_t* Kh = Kg + headTD;
    const uint16_t* Vh = Vtg + headTD;

    bf16x8 qf[4];
    {
        const uint16_t* qp = Qg + headTD + (size_t)(q0 + w * 16 + lr) * 128 + lg * 8;
#pragma unroll
        for (int kc = 0; kc < 4; ++kc) qf[kc] = *(const bf16x8*)(qp + kc * 32);
    }

    f32x4 accO[8];
#pragma unroll
    for (int i = 0; i < 8; ++i) accO[i] = (f32x4){0.f, 0.f, 0.f, 0.f};
    float mrun = -1e30f, lrun = 0.f;                 // per-lane row q = lr

    const float SL2E = 0.08838834764831845f * 1.4426950408889634f; // scale*log2e
    const int   swz  = (lr & 7) << 4;                // per-lane swizzle (row=lr)
    uint16_t* Pw = &Plds[w][0];

    auto STAGE = [&](int buf, int k0) {
#pragma unroll
        for (int p = 0; p < 4; ++p) {                // K: 64x128 rows of 256B
            int u = p * 256 + tid;                   // 16B chunk id
            int row = u >> 4;
            int c16 = (u & 15) ^ (row & 7);          // inverse swizzle on SOURCE
            gload_lds16(Kh + (size_t)(k0 + row) * 128 + c16 * 8,
                        (char*)&Klds[buf][0] + u * 16);
        }
#pragma unroll
        for (int p = 0; p < 4; ++p) {                // V: 128x64 rows of 128B
            int u = p * 256 + tid;
            int d = u >> 3;
            int c8 = (u & 7) ^ (d & 7);
            gload_lds16(Vh + (size_t)d * 2048 + k0 + c8 * 8,
                        (char*)&Vlds[buf][0] + u * 16);
        }
    };

    STAGE(0, 0);                                     // prologue

    for (int kt = 0; kt <= qt; ++kt) {
        asm volatile("s_waitcnt vmcnt(0)" ::: "memory"); // tile kt's loads done
        __builtin_amdgcn_s_barrier();
        __builtin_amdgcn_sched_barrier(0);
        if (kt < qt) STAGE((kt + 1) & 1, (kt + 1) * 64); // async prefetch

        const char* Kb = (const char*)&Klds[kt & 1][0];
        const char* Vb = (const char*)&Vlds[kt & 1][0];

        // ---- S^T = K Q^T : lane holds S[q=lr][k = cg*16 + lg*4 + r] ------
        float sv[4][4];
        __builtin_amdgcn_s_setprio(1);
#pragma unroll
        for (int cg = 0; cg < 4; ++cg) {
            f32x4 a = (f32x4){0.f, 0.f, 0.f, 0.f};
#pragma unroll
            for (int kc = 0; kc < 4; ++kc) {
                int kb = (cg * 16 + lr) * 256 + ((kc * 64 + lg * 16) ^ swz);
                bf16x8 kf = *(const bf16x8*)(Kb + kb);
                a = __builtin_amdgcn_mfma_f32_16x16x32_bf16(kf, qf[kc], a, 0, 0, 0);
            }
#pragma unroll
            for (int r = 0; r < 4; ++r) sv[cg][r] = a[r];
        }
        __builtin_amdgcn_s_setprio(0);

        if (kt == qt) {                              // causal mask, diagonal tile
#pragma unroll
            for (int cg = 0; cg < 4; ++cg)
#pragma unroll
                for (int r = 0; r < 4; ++r)
                    if (cg * 16 + lg * 4 + r > w * 16 + lr) sv[cg][r] = -1e30f;
        }

        // ---- defer-max online softmax (lane-local row) -------------------
        float pml = sv[0][0];
#pragma unroll
        for (int cg = 0; cg < 4; ++cg)
#pragma unroll
            for (int r = 0; r < 4; ++r) pml = fmaxf(pml, sv[cg][r]);

        if (!__all(pml * SL2E <= mrun + 11.f)) {     // rare: true max + rescale
            float mx = pml;
            mx = fmaxf(mx, __shfl_xor(mx, 16, 64));
            mx = fmaxf(mx, __shfl_xor(mx, 32, 64));  // full row max (q = lr)
            float mn = fmaxf(mrun, mx * SL2E);
            float corr = exp2f(mrun - mn);
            mrun = mn;
            lrun *= corr;                            // lane-partial sum scales too
            float ca[4];
#pragma unroll
            for (int r = 0; r < 4; ++r)              // corr for accO rows q=lg*4+r
                ca[r] = __shfl(corr, (lg << 4) + lg * 4 + r, 64);
#pragma unroll
            for (int i = 0; i < 8; ++i)
#pragma unroll
                for (int r = 0; r < 4; ++r) accO[i][r] *= ca[r];
        }

        float psum = 0.f;
        float p[4][4];
#pragma unroll
        for (int cg = 0; cg < 4; ++cg)
#pragma unroll
            for (int r = 0; r < 4; ++r) {
                p[cg][r] = exp2f(fmaf(sv[cg][r], SL2E, -mrun));
                psum += p[cg][r];
            }
        lrun += psum;

        // pack P pairs -> b64 LDS writes (row q=lr, k = 16cg+4lg .. +3)
#pragma unroll
        for (int cg = 0; cg < 4; ++cg) {
            uint32_t w0, w1;
            asm("v_cvt_pk_bf16_f32 %0, %1, %2" : "=v"(w0) : "v"(p[cg][0]), "v"(p[cg][1]));
            asm("v_cvt_pk_bf16_f32 %0, %1, %2" : "=v"(w1) : "v"(p[cg][2]), "v"(p[cg][3]));
            uint2 pr; pr.x = w0; pr.y = w1;
            *(uint2*)((char*)Pw + lr * 128 + ((cg * 32 + lg * 8) ^ swz)) = pr;
        }

        asm volatile("" ::: "memory");               // order P stores before reads
        bf16x8 pf[2];
#pragma unroll
        for (int c = 0; c < 2; ++c)
            pf[c] = *(const bf16x8*)((char*)Pw + lr * 128 + ((c * 64 + lg * 16) ^ swz));

        __builtin_amdgcn_s_setprio(1);
#pragma unroll
        for (int ni = 0; ni < 8; ++ni)
#pragma unroll
            for (int c = 0; c < 2; ++c) {
                int vb = (ni * 16 + lr) * 128 + ((c * 64 + lg * 16) ^ swz);
                bf16x8 vf = *(const bf16x8*)(Vb + vb);
                accO[ni] = __builtin_amdgcn_mfma_f32_16x16x32_bf16(pf[c], vf, accO[ni], 0, 0, 0);
            }
        __builtin_amdgcn_s_setprio(0);
    }

    // row sums: reduce lane-partials across the 4 lg lanes, then redistribute
    float lsum = lrun;
    lsum += __shfl_xor(lsum, 16, 64);
    lsum += __shfl_xor(lsum, 32, 64);                // full sum for row q = lr
    float linv = 1.f / lsum;
    float inv[4];
#pragma unroll
    for (int r = 0; r < 4; ++r)
        inv[r] = __shfl(linv, (lg << 4) + lg * 4 + r, 64); // for rows q=lg*4+r
    const int b = h >> 3, n = h & 7;
#pragma unroll
    for (int ni = 0; ni < 8; ++ni)
#pragma unroll
        for (int r = 0; r < 4; ++r) {
            int trow = q0 + w * 16 + lg * 4 + r;
            AOg[((size_t)(b * 2048 + trow)) * 1024 + n * 128 + ni * 16 + lr] =
                f2bf(accO[ni][r] * inv[r]);
        }
}

// ------------------------------- blade mixing epilogue (float4 + split-K add)
__global__ __launch_bounds__(256) void k_mix(const float* __restrict__ out0,
                                             const float* __restrict__ out1,
                                             const float* __restrict__ alpha,
                                             float* __restrict__ fin) {
    constexpr int SI[42] = {1,1,1,1,1,1, 2,2,2,2,2,2, 3,3,3,3,3,3, 4,4,4,4,4,4,
                            5,5,5,5,5,5, 6,6,6,6,6,6, 7,7,7,7,7,7};
    constexpr int SJ[42] = {2,3,4,5,6,7, 1,3,4,5,6,7, 1,2,4,5,6,7, 1,2,3,5,6,7,
                            1,2,3,4,6,7, 1,2,3,4,5,7, 1,2,3,4,5,6};
    constexpr int TG[42] = {4,5,2,3,7,6, 4,6,1,7,3,5, 5,6,7,1,2,4, 2,1,7,6,5,3,
                            3,7,1,6,4,2, 7,3,2,5,4,1, 6,5,4,3,2,1};
    constexpr float SG[42] = {+1,+1,+1,+1,+1,+1, -1,+1,-1,-1,+1,-1, -1,-1,+1,-1,-1,+1,
                              -1,+1,+1,-1,+1,-1, -1,-1,+1,+1,-1,+1, +1,-1,+1,-1,+1,-1,
                              +1,-1,+1,-1,+1,-1};
    int idx = blockIdx.x * 256 + threadIdx.x;        // B*T * 32 d-quads
    int dq = (idx & 31) * 4, bt = idx >> 5;
    size_t base = (size_t)bt * 1024 + dq;
    float4 o[8], r[8];
#pragma unroll
    for (int hh = 0; hh < 8; ++hh) {
        float4 a = *(const float4*)&out0[base + hh * 128];
        float4 b = *(const float4*)&out1[base + hh * 128];
        o[hh] = make_float4(a.x + b.x, a.y + b.y, a.z + b.z, a.w + b.w);
        r[hh] = o[hh];
    }
#pragma unroll
    for (int p = 0; p < 42; ++p) {
        float wgt = alpha[SI[p] * 8 + SJ[p]] * SG[p];
        r[TG[p]].x += wgt * o[SI[p]].x * o[SJ[p]].x;
        r[TG[p]].y += wgt * o[SI[p]].y * o[SJ[p]].y;
        r[TG[p]].z += wgt * o[SI[p]].z * o[SJ[p]].z;
        r[TG[p]].w += wgt * o[SI[p]].w * o[SJ[p]].w;
    }
#pragma unroll
    for (int hh = 0; hh < 8; ++hh) *(float4*)&fin[base + hh * 128] = r[hh];
}

// ---------------------------------------------------------------------------
extern "C" void kernel_launch(void* const* d_in, const int* in_sizes, int n_in,
                              void* d_out, int out_size, void* d_ws, size_t ws_size,
                              hipStream_t stream) {
    (void)in_sizes; (void)n_in; (void)out_size; (void)ws_size;
    const float* mv    = (const float*)d_in[0];
    const float* Wqkv  = (const float*)d_in[1];
    const float* Wo    = (const float*)d_in[2];
    const float* alpha = (const float*)d_in[3];
    float* outp = (float*)d_out;
    char* ws = (char*)d_ws;

    // workspace layout (bytes); AO overlays Xbf; outF0/outF1 live in the
    // region formerly used by QKV (now never written) + Qr (dead after attn).
    uint16_t* Xbf  = (uint16_t*)(ws + 0);            //  8 MB  [4096][1024]
    uint16_t* Wqt  = (uint16_t*)(ws + 8388608);      //  6 MB  [3072][1024]
    uint16_t* Wot  = (uint16_t*)(ws + 14680064);     //  2 MB  [1024][1024]
    uint16_t* Qr   = (uint16_t*)(ws + 41943040);     //  8 MB  [16][2048][128]
    uint16_t* Kr   = (uint16_t*)(ws + 50331648);     //  8 MB
    uint16_t* Vt   = (uint16_t*)(ws + 58720256);     //  8 MB  [16][128][2048]
    float*    ctab = (float*)(ws + 67108864);        // 0.5 MB
    float*    stab = (float*)(ws + 67633152);        // 0.5 MB
    uint16_t* AO   = (uint16_t*)(ws + 0);            // overlay (X dead after GEMM1)
    float*    outF0 = (float*)(ws + 16777216);       // 16 MB half 0
    float*    outF1 = (float*)(ws + 33554432);       // 16 MB half 1 (= outF0 + 4M floats)

    k_cast   <<<4096, 256, 0, stream>>>(mv, Xbf, 4096 * 1024);
    k_wtrans <<<dim3(48, 16), 256, 0, stream>>>(Wqkv, Wqt, 1024, 3072);
    k_wtrans <<<dim3(16, 16), 256, 0, stream>>>(Wo, Wot, 1024, 1024);
    k_tab    <<<512, 256, 0, stream>>>(ctab, stab);
    k_gemmqkv<<<dim3(24, 32), 256, 0, stream>>>(Xbf, Wqt, ctab, stab, Qr, Kr, Vt);
    k_attn   <<<512, 256, 0, stream>>>(Qr, Kr, Vt, AO);
    k_gemm2s <<<dim3(16, 32, 2), 256, 0, stream>>>(AO, Wot, outF0); // z=1 -> outF1
    k_mix    <<<512, 256, 0, stream>>>(outF0, outF1, alpha, outp);
}

// Round 12
// 121.469 us; speedup vs baseline: 2.3883x; 1.1023x over previous
//
#include <hip/hip_runtime.h>
#include <stdint.h>

// ---------------------------------------------------------------------------
// GeometricAttention: x@Wqkv (+fused RoPE/V-transpose epilogue) -> causal MHA
// -> @Wo (split-K, 128x64 tiles) -> blade mixing (float4).
// B=2 T=2048 N=8 D=128, d_model=1024. bf16 MFMA pipeline, fp32 accum.
// ---------------------------------------------------------------------------

typedef __attribute__((ext_vector_type(8)))  __bf16 bf16x8;
typedef __attribute__((ext_vector_type(4)))  float  f32x4;

__device__ __forceinline__ uint16_t f2bf(float f) {
    uint32_t u = __float_as_uint(f);
    u += 0x7FFFu + ((u >> 16) & 1u);           // RNE
    return (uint16_t)(u >> 16);
}
__device__ __forceinline__ float bf2f(uint16_t h) {
    return __uint_as_float(((uint32_t)h) << 16);
}

__device__ __forceinline__ void gload_lds16(const void* g, void* l) {
    __builtin_amdgcn_global_load_lds(
        (__attribute__((address_space(1))) void*)g,
        (__attribute__((address_space(3))) void*)l, 16, 0, 0);
}

// ----------------------- fused prologue: cast / weight-transpose / rope tables
// bid < 4096           : mv fp32 -> Xbf bf16 (float4/thread)
// 4096 <= bid < 4864   : Wqkv [1024][3072] -> Wqt [3072][1024] bf16
// 4864 <= bid < 5120   : Wo   [1024][1024] -> Wot [1024][1024] bf16
// bid >= 5120          : RoPE cos/sin tables (2048 x 64)
__global__ __launch_bounds__(256) void k_prep(const float* __restrict__ mv,
                                              const float* __restrict__ Wqkv,
                                              const float* __restrict__ Wo,
                                              uint16_t* __restrict__ Xbf,
                                              uint16_t* __restrict__ Wqt,
                                              uint16_t* __restrict__ Wot,
                                              float* __restrict__ ct,
                                              float* __restrict__ st) {
    __shared__ uint16_t tile[64][65];
    const int bid = blockIdx.x;
    const int tid = threadIdx.x;
    if (bid < 4096) {                                // cast
        int i = bid * 256 + tid;
        float4 v = ((const float4*)mv)[i];
        ((ushort4*)Xbf)[i] = make_ushort4(f2bf(v.x), f2bf(v.y), f2bf(v.z), f2bf(v.w));
    } else if (bid < 5120) {                         // weight transpose
        const float* W; uint16_t* Wt; int N, bx, by;
        if (bid < 4864) { W = Wqkv; Wt = Wqt; N = 3072;
                          int b2 = bid - 4096; bx = b2 % 48; by = b2 / 48; }
        else            { W = Wo;   Wt = Wot; N = 1024;
                          int b3 = bid - 4864; bx = b3 & 15; by = b3 >> 4; }
        const int k0 = by * 64, n0 = bx * 64;
        const int c = tid & 63, r4 = tid >> 6;
#pragma unroll
        for (int i = 0; i < 16; ++i) {
            int r = r4 + i * 4;
            tile[r][c] = f2bf(W[(size_t)(k0 + r) * N + n0 + c]);
        }
        __syncthreads();
#pragma unroll
        for (int i = 0; i < 16; ++i) {
            int r = r4 + i * 4;
            Wt[(size_t)(n0 + r) * 1024 + k0 + c] = tile[c][r];
        }
    } else {                                         // rope tables
        int i = (bid - 5120) * 256 + tid;            // 2048*64
        int t = i >> 6, f = i & 63;
        float inv = expf(-(float)f * 0.14391156830441f); // ln(10000)/64
        float ang = (float)t * inv;
        ct[i] = cosf(ang);
        st[i] = sinf(ang);
    }
}

// ---------------------- QKV GEMM (BK=64, swizzled LDS) + RoPE/V-T epilogue
// XCD-aware swizzle (T1): 768 blocks, bijective. BK=64: 16 k-iters (half the
// barrier drains of BK=32). A/B tiles stored XOR-swizzled (slot = chunk ^
// (row&7), inverse-swizzle applied on the GLOBAL source — rule 21) so the
// stride-128B b128 fragment reads stay at the 8-cycle b128 floor instead of
// 16-way serialization. Epilogue Tl overlays Atile/Btile (union via smem):
// LDS 49.8 -> 33.8 KB => 4 blocks/CU. n-tile: sec = n>>3 (0=Q,1=K,2=V),
// head = n&7; rope pairs (d,d+64) tile-local. Q/K roped [h][T][128]; V
// transposed [h][128][T].
__global__ __launch_bounds__(256) void k_gemmqkv(const uint16_t* __restrict__ A,
                                                 const uint16_t* __restrict__ Bt,
                                                 const float* __restrict__ ct,
                                                 const float* __restrict__ st,
                                                 uint16_t* __restrict__ Qr,
                                                 uint16_t* __restrict__ Kr,
                                                 uint16_t* __restrict__ Vt) {
    __shared__ __align__(16) char smem[33792];       // loop: 32KB A+B; epi: Tl
    uint16_t* Atile = (uint16_t*)smem;               // [128][64] swizzled
    uint16_t* Btile = (uint16_t*)(smem + 16384);     // [128][64] swizzled
    const int lin = blockIdx.y * 24 + blockIdx.x;
    const int logical = (lin & 7) * 96 + (lin >> 3); // XCD swizzle (bijective)
    const int bx = logical % 24;                     // n-tile 0..23
    const int m0 = (logical / 24) << 7, n0 = bx << 7;
    const int sec = bx >> 3, head = bx & 7;
    const int tid = threadIdx.x;
    const int l = tid & 63, w = tid >> 6;
    const int lr = l & 15, lg = l >> 4;
    const int wm = (w >> 1) << 6, wn = (w & 1) << 6;
    const int K = 1024;

    f32x4 acc[4][4];
#pragma unroll
    for (int i = 0; i < 4; ++i)
#pragma unroll
        for (int j = 0; j < 4; ++j) acc[i][j] = (f32x4){0.f, 0.f, 0.f, 0.f};

    for (int kt = 0; kt < 16; ++kt) {                // K = 16 x 64
        const int k0 = kt << 6;
        __syncthreads();
#pragma unroll
        for (int c = 0; c < 8; ++c) {                // 2048 16B chunks
            int idx = c * 256 + tid;
            if (idx < 1024) {                        // A: row r, chunk c16
                int r = idx >> 3, c16 = idx & 7;
                int sc = c16 ^ (r & 7);              // inverse swizzle on SOURCE
                gload_lds16(A + (size_t)(m0 + r) * K + k0 + sc * 8, Atile + idx * 8);
            } else {
                int i2 = idx - 1024;
                int r = i2 >> 3, c16 = i2 & 7;
                int sc = c16 ^ (r & 7);
                gload_lds16(Bt + (size_t)(n0 + r) * K + k0 + sc * 8, Btile + i2 * 8);
            }
        }
        __syncthreads();
#pragma unroll
        for (int kk = 0; kk < 2; ++kk) {
            bf16x8 af[4], bfv[4];
#pragma unroll
            for (int i = 0; i < 4; ++i) {
                int ra = wm + i * 16 + lr;
                af[i]  = *(const bf16x8*)((char*)Atile + ra * 128 +
                          ((kk * 64 + lg * 16) ^ ((ra & 7) << 4)));
                int rb = wn + i * 16 + lr;
                bfv[i] = *(const bf16x8*)((char*)Btile + rb * 128 +
                          ((kk * 64 + lg * 16) ^ ((rb & 7) << 4)));
            }
#pragma unroll
            for (int mi = 0; mi < 4; ++mi)
#pragma unroll
                for (int ni = 0; ni < 4; ++ni)
                    acc[mi][ni] = __builtin_amdgcn_mfma_f32_16x16x32_bf16(
                        af[mi], bfv[ni], acc[mi][ni], 0, 0, 0);
        }
    }

    // ---- epilogue: acc -> LDS bf16 tile (overlays Atile/Btile; safe after
    // syncthreads: all ds_reads of the last iter have completed)
    __syncthreads();
    uint16_t (*Tl)[132] = (uint16_t(*)[132])smem;    // [128][132], 33792 B
#pragma unroll
    for (int mi = 0; mi < 4; ++mi)
#pragma unroll
        for (int ni = 0; ni < 4; ++ni)
#pragma unroll
            for (int r = 0; r < 4; ++r)
                Tl[wm + mi * 16 + lg * 4 + r][wn + ni * 16 + lr] =
                    f2bf(acc[mi][ni][r]);
    __syncthreads();

    const int b = m0 >> 11, t0 = m0 & 2047;
    const size_t hidx = (size_t)(b * 8 + head);
    if (sec < 2) {                                   // Q or K: rope + write
        uint16_t* outp = (sec == 0 ? Qr : Kr) + (hidx * 2048 + t0) * 128;
#pragma unroll
        for (int it = 0; it < 8; ++it) {
            int lin2 = it * 256 + tid;
            int tr = lin2 >> 4, d0 = (lin2 & 15) * 4;
            ushort4 lo = *(const ushort4*)&Tl[tr][d0];
            ushort4 hi = *(const ushort4*)&Tl[tr][d0 + 64];
            float4 cv = *(const float4*)&ct[(size_t)(t0 + tr) * 64 + d0];
            float4 sv = *(const float4*)&st[(size_t)(t0 + tr) * 64 + d0];
            ushort4 o1, o2;
            o1.x = f2bf(bf2f(lo.x) * cv.x - bf2f(hi.x) * sv.x);
            o2.x = f2bf(bf2f(hi.x) * cv.x + bf2f(lo.x) * sv.x);
            o1.y = f2bf(bf2f(lo.y) * cv.y - bf2f(hi.y) * sv.y);
            o2.y = f2bf(bf2f(hi.y) * cv.y + bf2f(lo.y) * sv.y);
            o1.z = f2bf(bf2f(lo.z) * cv.z - bf2f(hi.z) * sv.z);
            o2.z = f2bf(bf2f(hi.z) * cv.z + bf2f(lo.z) * sv.z);
            o1.w = f2bf(bf2f(lo.w) * cv.w - bf2f(hi.w) * sv.w);
            o2.w = f2bf(bf2f(hi.w) * cv.w + bf2f(lo.w) * sv.w);
            *(ushort4*)&outp[(size_t)tr * 128 + d0]      = o1;
            *(ushort4*)&outp[(size_t)tr * 128 + d0 + 64] = o2;
        }
    } else {                                         // V: transpose to [h][D][T]
        uint16_t* vp = Vt + hidx * 128 * 2048;
#pragma unroll
        for (int it = 0; it < 8; ++it) {
            int lin2 = it * 256 + tid;
            int d = lin2 >> 4, tq = (lin2 & 15) * 8;
            ushort4 v0 = make_ushort4(Tl[tq + 0][d], Tl[tq + 1][d],
                                      Tl[tq + 2][d], Tl[tq + 3][d]);
            ushort4 v1 = make_ushort4(Tl[tq + 4][d], Tl[tq + 5][d],
                                      Tl[tq + 6][d], Tl[tq + 7][d]);
            *(ushort4*)&vp[(size_t)d * 2048 + t0 + tq]     = v0;
            *(ushort4*)&vp[(size_t)d * 2048 + t0 + tq + 4] = v1;
        }
    }
}

// ------------------- split-K out-proj GEMM, 128x64 tiles, BK=64, swizzled
// grid (16,32,2) = 1024 blocks = 4 blocks/CU. 8 k-iters per half. Same
// XOR-swizzled tiles as k_gemmqkv. Halves write C / C + 4M floats.
__global__ __launch_bounds__(256) void k_gemm2s(const uint16_t* __restrict__ A,
                                                const uint16_t* __restrict__ Bt,
                                                float* __restrict__ C) {
    __shared__ uint16_t Atile[128 * 64];             // 16 KB swizzled
    __shared__ uint16_t Btile[64 * 64];              //  8 KB swizzled
    const int kz = blockIdx.z;
    A  += (size_t)kz * 512;                          // k-offset within row
    Bt += (size_t)kz * 512;
    C  += (size_t)kz * (4096u * 1024u);              // partial-output buffer
    const int lin = blockIdx.y * 16 + blockIdx.x;
    const int logical = (lin & 7) * 64 + (lin >> 3); // XCD swizzle per z
    const int m0 = (logical >> 4) << 7, n0 = (logical & 15) << 6;
    const int tid = threadIdx.x;
    const int l = tid & 63, w = tid >> 6;
    const int lr = l & 15, lg = l >> 4;
    const int wm = (w >> 1) << 6, wn = (w & 1) << 5;

    f32x4 acc[4][2];
#pragma unroll
    for (int i = 0; i < 4; ++i)
#pragma unroll
        for (int j = 0; j < 2; ++j) acc[i][j] = (f32x4){0.f, 0.f, 0.f, 0.f};

    for (int kt = 0; kt < 8; ++kt) {                 // K_half = 512 = 8 x 64
        const int k0 = kt << 6;
        __syncthreads();
#pragma unroll
        for (int c = 0; c < 6; ++c) {                // 1536 16B chunks
            int idx = c * 256 + tid;
            if (idx < 1024) {                        // A: 128 rows x 8 chunks
                int r = idx >> 3, c16 = idx & 7;
                int sc = c16 ^ (r & 7);
                gload_lds16(A + (size_t)(m0 + r) * 1024 + k0 + sc * 8, Atile + idx * 8);
            } else {                                 // B: 64 rows x 8 chunks
                int i2 = idx - 1024;
                int r = i2 >> 3, c16 = i2 & 7;
                int sc = c16 ^ (r & 7);
                gload_lds16(Bt + (size_t)(n0 + r) * 1024 + k0 + sc * 8, Btile + i2 * 8);
            }
        }
        __syncthreads();
#pragma unroll
        for (int kk = 0; kk < 2; ++kk) {
            bf16x8 af[4], bfv[2];
#pragma unroll
            for (int i = 0; i < 4; ++i) {
                int ra = wm + i * 16 + lr;
                af[i] = *(const bf16x8*)((char*)Atile + ra * 128 +
                         ((kk * 64 + lg * 16) ^ ((ra & 7) << 4)));
            }
#pragma unroll
            for (int j = 0; j < 2; ++j) {
                int rb = wn + j * 16 + lr;
                bfv[j] = *(const bf16x8*)((char*)Btile + rb * 128 +
                          ((kk * 64 + lg * 16) ^ ((rb & 7) << 4)));
            }
#pragma unroll
            for (int mi = 0; mi < 4; ++mi)
#pragma unroll
                for (int ni = 0; ni < 2; ++ni)
                    acc[mi][ni] = __builtin_amdgcn_mfma_f32_16x16x32_bf16(
                        af[mi], bfv[ni], acc[mi][ni], 0, 0, 0);
        }
    }
#pragma unroll
    for (int mi = 0; mi < 4; ++mi)
#pragma unroll
        for (int ni = 0; ni < 2; ++ni)
#pragma unroll
            for (int r = 0; r < 4; ++r) {
                int row = m0 + wm + mi * 16 + lg * 4 + r;
                int col = n0 + wn + ni * 16 + lr;
                C[(size_t)row * 1024 + col] = acc[mi][ni][r];
            }
}

// --------------------------------------------------- causal flash attention
// R3-proven kernel (58 us): swapped QK^T (S^T = mfma(K,Q)) so each lane holds
// P[q=lr][16 k] lane-locally; softmax state scalar/lane, common path has NO
// cross-lane ops. P -> LDS as packed b64 (cvt_pk_bf16 pairs), read back as
// swizzled b128 A-frags. K/V double-buffered via global_load_lds (linear
// dest, inverse-swizzled src). Heavy/light block pairing.
__global__ __launch_bounds__(256) void k_attn(const uint16_t* __restrict__ Qg,
                                              const uint16_t* __restrict__ Kg,
                                              const uint16_t* __restrict__ Vtg,
                                              uint16_t* __restrict__ AOg) {
    __shared__ uint16_t Klds[2][64 * 128];           // 16 KB each, XOR-swizzled
    __shared__ uint16_t Vlds[2][128 * 64];           // 16 KB each, XOR-swizzled
    __shared__ uint16_t Plds[4][16 * 64];            // 2 KB per wave, swizzled

    const int bx = blockIdx.x;
    const int h  = bx & 15;
    const int t4 = (bx >> 4) & 15;
    const int qt = (bx < 256) ? (31 - t4) : t4;      // heavy/light pairing
    const int q0 = qt * 64;
    const int tid = threadIdx.x;
    const int l = tid & 63, w = tid >> 6;
    const int lr = l & 15, lg = l >> 4;
    const size_t headTD = (size_t)h * (2048 * 128);
    const uint16_t* Kh = Kg + headTD;
    const uint16_t* Vh = Vtg + headTD;

    bf16x8 qf[4];
    {
        const uint16_t* qp = Qg + headTD + (size_t)(q0 + w * 16 + lr) * 128 + lg * 8;
#pragma unroll
        for (int kc = 0; kc < 4; ++kc) qf[kc] = *(const bf16x8*)(qp + kc * 32);
    }

    f32x4 accO[8];
#pragma unroll
    for (int i = 0; i < 8; ++i) accO[i] = (f32x4){0.f, 0.f, 0.f, 0.f};
    float mrun = -1e30f, lrun = 0.f;                 // per-lane row q = lr

    const float SL2E = 0.08838834764831845f * 1.4426950408889634f; // scale*log2e
    const int   swz  = (lr & 7) << 4;                // per-lane swizzle (row=lr)
    uint16_t* Pw = &Plds[w][0];

    auto STAGE = [&](int buf, int k0) {
#pragma unroll
        for (int p = 0; p < 4; ++p) {                // K: 64x128 rows of 256B
            int u = p * 256 + tid;                   // 16B chunk id
            int row = u >> 4;
            int c16 = (u & 15) ^ (row & 7);          // inverse swizzle on SOURCE
            gload_lds16(Kh + (size_t)(k0 + row) * 128 + c16 * 8,
                        (char*)&Klds[buf][0] + u * 16);
        }
#pragma unroll
        for (int p = 0; p < 4; ++p) {                // V: 128x64 rows of 128B
            int u = p * 256 + tid;
            int d = u >> 3;
            int c8 = (u & 7) ^ (d & 7);
            gload_lds16(Vh + (size_t)d * 2048 + k0 + c8 * 8,
                        (char*)&Vlds[buf][0] + u * 16);
        }
    };

    STAGE(0, 0);                                     // prologue

    for (int kt = 0; kt <= qt; ++kt) {
        asm volatile("s_waitcnt vmcnt(0)" ::: "memory"); // tile kt's loads done
        __builtin_amdgcn_s_barrier();
        __builtin_amdgcn_sched_barrier(0);
        if (kt < qt) STAGE((kt + 1) & 1, (kt + 1) * 64); // async prefetch

        const char* Kb = (const char*)&Klds[kt & 1][0];
        const char* Vb = (const char*)&Vlds[kt & 1][0];

        // ---- S^T = K Q^T : lane holds S[q=lr][k = cg*16 + lg*4 + r] ------
        float sv[4][4];
        __builtin_amdgcn_s_setprio(1);
#pragma unroll
        for (int cg = 0; cg < 4; ++cg) {
            f32x4 a = (f32x4){0.f, 0.f, 0.f, 0.f};
#pragma unroll
            for (int kc = 0; kc < 4; ++kc) {
                int kb = (cg * 16 + lr) * 256 + ((kc * 64 + lg * 16) ^ swz);
                bf16x8 kf = *(const bf16x8*)(Kb + kb);
                a = __builtin_amdgcn_mfma_f32_16x16x32_bf16(kf, qf[kc], a, 0, 0, 0);
            }
#pragma unroll
            for (int r = 0; r < 4; ++r) sv[cg][r] = a[r];
        }
        __builtin_amdgcn_s_setprio(0);

        if (kt == qt) {                              // causal mask, diagonal tile
#pragma unroll
            for (int cg = 0; cg < 4; ++cg)
#pragma unroll
                for (int r = 0; r < 4; ++r)
                    if (cg * 16 + lg * 4 + r > w * 16 + lr) sv[cg][r] = -1e30f;
        }

        // ---- defer-max online softmax (lane-local row) -------------------
        float pml = sv[0][0];
#pragma unroll
        for (int cg = 0; cg < 4; ++cg)
#pragma unroll
            for (int r = 0; r < 4; ++r) pml = fmaxf(pml, sv[cg][r]);

        if (!__all(pml * SL2E <= mrun + 11.f)) {     // rare: true max + rescale
            float mx = pml;
            mx = fmaxf(mx, __shfl_xor(mx, 16, 64));
            mx = fmaxf(mx, __shfl_xor(mx, 32, 64));  // full row max (q = lr)
            float mn = fmaxf(mrun, mx * SL2E);
            float corr = exp2f(mrun - mn);
            mrun = mn;
            lrun *= corr;                            // lane-partial sum scales too
            float ca[4];
#pragma unroll
            for (int r = 0; r < 4; ++r)              // corr for accO rows q=lg*4+r
                ca[r] = __shfl(corr, (lg << 4) + lg * 4 + r, 64);
#pragma unroll
            for (int i = 0; i < 8; ++i)
#pragma unroll
                for (int r = 0; r < 4; ++r) accO[i][r] *= ca[r];
        }

        float psum = 0.f;
        float p[4][4];
#pragma unroll
        for (int cg = 0; cg < 4; ++cg)
#pragma unroll
            for (int r = 0; r < 4; ++r) {
                p[cg][r] = exp2f(fmaf(sv[cg][r], SL2E, -mrun));
                psum += p[cg][r];
            }
        lrun += psum;

        // pack P pairs -> b64 LDS writes (row q=lr, k = 16cg+4lg .. +3)
#pragma unroll
        for (int cg = 0; cg < 4; ++cg) {
            uint32_t w0, w1;
            asm("v_cvt_pk_bf16_f32 %0, %1, %2" : "=v"(w0) : "v"(p[cg][0]), "v"(p[cg][1]));
            asm("v_cvt_pk_bf16_f32 %0, %1, %2" : "=v"(w1) : "v"(p[cg][2]), "v"(p[cg][3]));
            uint2 pr; pr.x = w0; pr.y = w1;
            *(uint2*)((char*)Pw + lr * 128 + ((cg * 32 + lg * 8) ^ swz)) = pr;
        }

        asm volatile("" ::: "memory");               // order P stores before reads
        bf16x8 pf[2];
#pragma unroll
        for (int c = 0; c < 2; ++c)
            pf[c] = *(const bf16x8*)((char*)Pw + lr * 128 + ((c * 64 + lg * 16) ^ swz));

        __builtin_amdgcn_s_setprio(1);
#pragma unroll
        for (int ni = 0; ni < 8; ++ni)
#pragma unroll
            for (int c = 0; c < 2; ++c) {
                int vb = (ni * 16 + lr) * 128 + ((c * 64 + lg * 16) ^ swz);
                bf16x8 vf = *(const bf16x8*)(Vb + vb);
                accO[ni] = __builtin_amdgcn_mfma_f32_16x16x32_bf16(pf[c], vf, accO[ni], 0, 0, 0);
            }
        __builtin_amdgcn_s_setprio(0);
    }

    // row sums: reduce lane-partials across the 4 lg lanes, then redistribute
    float lsum = lrun;
    lsum += __shfl_xor(lsum, 16, 64);
    lsum += __shfl_xor(lsum, 32, 64);                // full sum for row q = lr
    float linv = 1.f / lsum;
    float inv[4];
#pragma unroll
    for (int r = 0; r < 4; ++r)
        inv[r] = __shfl(linv, (lg << 4) + lg * 4 + r, 64); // for rows q=lg*4+r
    const int b = h >> 3, n = h & 7;
#pragma unroll
    for (int ni = 0; ni < 8; ++ni)
#pragma unroll
        for (int r = 0; r < 4; ++r) {
            int trow = q0 + w * 16 + lg * 4 + r;
            AOg[((size_t)(b * 2048 + trow)) * 1024 + n * 128 + ni * 16 + lr] =
                f2bf(accO[ni][r] * inv[r]);
        }
}

// ------------------------------- blade mixing epilogue (float4 + split-K add)
__global__ __launch_bounds__(256) void k_mix(const float* __restrict__ out0,
                                             const float* __restrict__ out1,
                                             const float* __restrict__ alpha,
                                             float* __restrict__ fin) {
    constexpr int SI[42] = {1,1,1,1,1,1, 2,2,2,2,2,2, 3,3,3,3,3,3, 4,4,4,4,4,4,
                            5,5,5,5,5,5, 6,6,6,6,6,6, 7,7,7,7,7,7};
    constexpr int SJ[42] = {2,3,4,5,6,7, 1,3,4,5,6,7, 1,2,4,5,6,7, 1,2,3,5,6,7,
                            1,2,3,4,6,7, 1,2,3,4,5,7, 1,2,3,4,5,6};
    constexpr int TG[42] = {4,5,2,3,7,6, 4,6,1,7,3,5, 5,6,7,1,2,4, 2,1,7,6,5,3,
                            3,7,1,6,4,2, 7,3,2,5,4,1, 6,5,4,3,2,1};
    constexpr float SG[42] = {+1,+1,+1,+1,+1,+1, -1,+1,-1,-1,+1,-1, -1,-1,+1,-1,-1,+1,
                              -1,+1,+1,-1,+1,-1, -1,-1,+1,+1,-1,+1, +1,-1,+1,-1,+1,-1,
                              +1,-1,+1,-1,+1,-1};
    int idx = blockIdx.x * 256 + threadIdx.x;        // B*T * 32 d-quads
    int dq = (idx & 31) * 4, bt = idx >> 5;
    size_t base = (size_t)bt * 1024 + dq;
    float4 o[8], r[8];
#pragma unroll
    for (int hh = 0; hh < 8; ++hh) {
        float4 a = *(const float4*)&out0[base + hh * 128];
        float4 b = *(const float4*)&out1[base + hh * 128];
        o[hh] = make_float4(a.x + b.x, a.y + b.y, a.z + b.z, a.w + b.w);
        r[hh] = o[hh];
    }
#pragma unroll
    for (int p = 0; p < 42; ++p) {
        float wgt = alpha[SI[p] * 8 + SJ[p]] * SG[p];
        r[TG[p]].x += wgt * o[SI[p]].x * o[SJ[p]].x;
        r[TG[p]].y += wgt * o[SI[p]].y * o[SJ[p]].y;
        r[TG[p]].z += wgt * o[SI[p]].z * o[SJ[p]].z;
        r[TG[p]].w += wgt * o[SI[p]].w * o[SJ[p]].w;
    }
#pragma unroll
    for (int hh = 0; hh < 8; ++hh) *(float4*)&fin[base + hh * 128] = r[hh];
}

// ---------------------------------------------------------------------------
extern "C" void kernel_launch(void* const* d_in, const int* in_sizes, int n_in,
                              void* d_out, int out_size, void* d_ws, size_t ws_size,
                              hipStream_t stream) {
    (void)in_sizes; (void)n_in; (void)out_size; (void)ws_size;
    const float* mv    = (const float*)d_in[0];
    const float* Wqkv  = (const float*)d_in[1];
    const float* Wo    = (const float*)d_in[2];
    const float* alpha = (const float*)d_in[3];
    float* outp = (float*)d_out;
    char* ws = (char*)d_ws;

    // workspace layout (bytes); AO overlays Xbf; outF0/outF1 live in the
    // region formerly used by QKV (now never written) + Qr (dead after attn).
    uint16_t* Xbf  = (uint16_t*)(ws + 0);            //  8 MB  [4096][1024]
    uint16_t* Wqt  = (uint16_t*)(ws + 8388608);      //  6 MB  [3072][1024]
    uint16_t* Wot  = (uint16_t*)(ws + 14680064);     //  2 MB  [1024][1024]
    uint16_t* Qr   = (uint16_t*)(ws + 41943040);     //  8 MB  [16][2048][128]
    uint16_t* Kr   = (uint16_t*)(ws + 50331648);     //  8 MB
    uint16_t* Vt   = (uint16_t*)(ws + 58720256);     //  8 MB  [16][128][2048]
    float*    ctab = (float*)(ws + 67108864);        // 0.5 MB
    float*    stab = (float*)(ws + 67633152);        // 0.5 MB
    uint16_t* AO   = (uint16_t*)(ws + 0);            // overlay (X dead after GEMM1)
    float*    outF0 = (float*)(ws + 16777216);       // 16 MB half 0
    float*    outF1 = (float*)(ws + 33554432);       // 16 MB half 1 (= outF0 + 4M floats)

    k_prep   <<<5632, 256, 0, stream>>>(mv, Wqkv, Wo, Xbf, Wqt, Wot, ctab, stab);
    k_gemmqkv<<<dim3(24, 32), 256, 0, stream>>>(Xbf, Wqt, ctab, stab, Qr, Kr, Vt);
    k_attn   <<<512, 256, 0, stream>>>(Qr, Kr, Vt, AO);
    k_gemm2s <<<dim3(16, 32, 2), 256, 0, stream>>>(AO, Wot, outF0); // z=1 -> outF1
    k_mix    <<<512, 256, 0, stream>>>(outF0, outF1, alpha, outp);
}